// Round 1
// baseline (1836.430 us; speedup 1.0000x reference)
//
#include <hip/hip_runtime.h>
#include <math.h>

#define NN 100000
#define NE 1250000
#define HD 64
#define NCLS 129

// ---------------- degree / norm ----------------
__global__ void k_deg(const int* __restrict__ src, const int* __restrict__ dst,
                      int* __restrict__ dego, int* __restrict__ degi, int e) {
    int i = blockIdx.x * blockDim.x + threadIdx.x;
    if (i < e) {
        atomicAdd(&dego[src[i]], 1);
        atomicAdd(&degi[dst[i]], 1);
    }
}

__global__ void k_norms(const int* __restrict__ dego, const int* __restrict__ degi,
                        float* __restrict__ ns, float* __restrict__ nd, int n) {
    int i = blockIdx.x * blockDim.x + threadIdx.x;
    if (i < n) {
        int a = dego[i]; if (a < 1) a = 1;
        int b = degi[i]; if (b < 1) b = 1;
        ns[i] = rsqrtf((float)a);
        nd[i] = rsqrtf((float)b);
    }
}

// ---------------- prefix scan (3-phase) ----------------
__global__ void k_scan_local(const int* __restrict__ deg, int* __restrict__ excl,
                             int* __restrict__ bsums, int n) {
    __shared__ int sm[1024];
    int t = threadIdx.x;
    int i = blockIdx.x * 1024 + t;
    int v = (i < n) ? deg[i] : 0;
    sm[t] = v;
    __syncthreads();
    for (int ofs = 1; ofs < 1024; ofs <<= 1) {
        int x = (t >= ofs) ? sm[t - ofs] : 0;
        __syncthreads();
        sm[t] += x;
        __syncthreads();
    }
    if (i < n) excl[i] = sm[t] - v;
    if (t == 1023) bsums[blockIdx.x] = sm[1023];
}

__global__ void k_scan_tops(int* __restrict__ bsums, int nb) {
    __shared__ int sm[1024];
    int t = threadIdx.x;
    int v = (t < nb) ? bsums[t] : 0;
    sm[t] = v;
    __syncthreads();
    for (int ofs = 1; ofs < 1024; ofs <<= 1) {
        int x = (t >= ofs) ? sm[t - ofs] : 0;
        __syncthreads();
        sm[t] += x;
        __syncthreads();
    }
    if (t < nb) bsums[t] = sm[t] - v;  // exclusive
}

__global__ void k_scan_add(int* __restrict__ excl, const int* __restrict__ bsums,
                           int n, int total) {
    int i = blockIdx.x * blockDim.x + threadIdx.x;
    if (i < n) excl[i] += bsums[i >> 10];
    if (i == 0) excl[n] = total;
}

__global__ void k_csr_fill(const int* __restrict__ src, const int* __restrict__ dst,
                           const int* __restrict__ rowptr, int* __restrict__ cursor,
                           int* __restrict__ col, int e) {
    int i = blockIdx.x * blockDim.x + threadIdx.x;
    if (i < e) {
        int d = dst[i];
        int p = atomicAdd(&cursor[d], 1);
        col[rowptr[d] + p] = src[i];
    }
}

// ---------------- gather-aggregate: agg[n][f] = sum_{src in N(n)} x[src][f]*ns[src]
__global__ __launch_bounds__(256) void k_gather(
    const float* __restrict__ x, const float* __restrict__ ns,
    const int* __restrict__ rowptr, const int* __restrict__ col,
    float* __restrict__ agg, int n) {
    int w = (blockIdx.x * 256 + threadIdx.x) >> 6;
    int lane = threadIdx.x & 63;
    if (w >= n) return;
    int beg = rowptr[w], end = rowptr[w + 1];
    float s = 0.f;
    for (int e = beg; e < end; ++e) {
        int c = col[e];
        s += x[(size_t)c * HD + lane] * ns[c];
    }
    agg[(size_t)w * HD + lane] = s;
}

// ---------------- y = ELU((agg*nd) @ W + b), in place, + column sum/sumsq stats
__global__ __launch_bounds__(256) void k_lin_elu_stats(
    float* __restrict__ y, const float* __restrict__ nd,
    const float* __restrict__ W, const float* __restrict__ b,
    float* __restrict__ stats, int n) {
    __shared__ float sW[HD * HD];
    __shared__ float red[256];
    int t = threadIdx.x;
    for (int i = t; i < HD * HD; i += 256) sW[i] = W[i];
    int o = t & 63, nl = t >> 6;
    float bo = b[o];
    float lsum = 0.f, lsq = 0.f;
    __syncthreads();
    int node0 = blockIdx.x * 32;
    for (int it = 0; it < 8; ++it) {
        int node = node0 + it * 4 + nl;
        if (node < n) {
            float xo = y[(size_t)node * HD + o] * nd[node];
            float acc = bo;
#pragma unroll
            for (int k = 0; k < HD; ++k)
                acc += __shfl(xo, k, 64) * sW[k * HD + o];
            acc = acc > 0.f ? acc : expm1f(acc);
            y[(size_t)node * HD + o] = acc;
            lsum += acc;
            lsq += acc * acc;
        }
    }
    red[t] = lsum;
    __syncthreads();
    if (nl == 0) atomicAdd(&stats[o], red[o] + red[64 + o] + red[128 + o] + red[192 + o]);
    __syncthreads();
    red[t] = lsq;
    __syncthreads();
    if (nl == 0) atomicAdd(&stats[64 + o], red[o] + red[64 + o] + red[128 + o] + red[192 + o]);
}

// ---------------- BN apply in place
__global__ void k_bn(float* __restrict__ y, const float* __restrict__ stats,
                     const float* __restrict__ g, const float* __restrict__ bt, int n) {
    int i = blockIdx.x * blockDim.x + threadIdx.x;  // over n*16 (float4)
    if (i >= n * 16) return;
    int o4 = (i & 15) * 4;
    float4 v = ((const float4*)y)[i];
    float* vv = (float*)&v;
    float invN = 1.f / (float)n;
#pragma unroll
    for (int j = 0; j < 4; ++j) {
        int o = o4 + j;
        float mu = stats[o] * invN;
        float var = stats[64 + o] * invN - mu * mu;
        var = fmaxf(var, 0.f);
        vv[j] = (vv[j] - mu) * rsqrtf(var + 1e-5f) * g[o] + bt[o];
    }
    ((float4*)y)[i] = v;
}

// ---------------- z = PReLU(cat(h1,h2,|h1-h2|,h1*h2) @ gW1 + gb1)
__global__ __launch_bounds__(256) void k_comb1(
    const float* __restrict__ h1b, const float* __restrict__ h2b,
    const float* __restrict__ W /*256x64*/, const float* __restrict__ bias,
    const float* __restrict__ pa, float* __restrict__ z, int n) {
    __shared__ float sW[128 * 64];  // 32KB, two k-chunks
    int t = threadIdx.x, o = t & 63, nl = t >> 6;
    float bo = bias[o], slope = pa[0];
    int node0 = blockIdx.x * 32;
    float h1o[8], h2o[8], acc[8];
#pragma unroll
    for (int it = 0; it < 8; ++it) {
        int node = node0 + it * 4 + nl;
        bool ok = node < n;
        h1o[it] = ok ? h1b[(size_t)node * HD + o] : 0.f;
        h2o[it] = ok ? h2b[(size_t)node * HD + o] : 0.f;
        acc[it] = bo;
    }
    for (int c = 0; c < 2; ++c) {
        for (int i = t; i < 128 * 64; i += 256) {
            int r = i >> 6;
            int q = r >> 5, k = (r & 31) + c * 32;
            sW[i] = W[(q * 64 + k) * 64 + (i & 63)];
        }
        __syncthreads();
        for (int it = 0; it < 8; ++it) {
#pragma unroll
            for (int kk = 0; kk < 32; ++kk) {
                int k = c * 32 + kk;
                float a1 = __shfl(h1o[it], k, 64);
                float a2 = __shfl(h2o[it], k, 64);
                float ad = fabsf(a1 - a2), ap = a1 * a2;
                acc[it] += a1 * sW[kk * 64 + o] + a2 * sW[(32 + kk) * 64 + o] +
                           ad * sW[(64 + kk) * 64 + o] + ap * sW[(96 + kk) * 64 + o];
            }
        }
        __syncthreads();
    }
#pragma unroll
    for (int it = 0; it < 8; ++it) {
        int node = node0 + it * 4 + nl;
        if (node < n) {
            float v = acc[it];
            z[(size_t)node * HD + o] = v > 0.f ? v : slope * v;
        }
    }
}

// ---------------- gate = sigmoid(z @ gW2 + gb2); fused = gate*h1+(1-gate)*h2 (in place over z)
__global__ __launch_bounds__(256) void k_comb2(
    float* __restrict__ z, const float* __restrict__ h1, const float* __restrict__ h2,
    const float* __restrict__ W2, const float* __restrict__ b2, int n) {
    __shared__ float sW[HD * HD];
    int t = threadIdx.x;
    for (int i = t; i < HD * HD; i += 256) sW[i] = W2[i];
    int o = t & 63;
    float bo = b2[o];
    __syncthreads();
    int node0 = blockIdx.x * 32;
    for (int it = 0; it < 8; ++it) {
        int node = node0 + it * 4 + (t >> 6);
        if (node < n) {
            float zo = z[(size_t)node * HD + o];
            float acc = bo;
#pragma unroll
            for (int k = 0; k < HD; ++k)
                acc += __shfl(zo, k, 64) * sW[k * HD + o];
            float gate = 1.f / (1.f + expf(-acc));
            float f = gate * h1[(size_t)node * HD + o] + (1.f - gate) * h2[(size_t)node * HD + o];
            z[(size_t)node * HD + o] = f;
        }
    }
}

// ---------------- out = fused @ fcW + fcb  (64 -> 129)
__global__ __launch_bounds__(256) void k_fc(
    const float* __restrict__ fused, const float* __restrict__ W /*64x129*/,
    const float* __restrict__ b, float* __restrict__ out, int n) {
    __shared__ float sW[HD * NCLS];
    __shared__ float sb[NCLS];
    __shared__ float sx[8][HD];
    int t = threadIdx.x;
    for (int i = t; i < HD * NCLS; i += 256) sW[i] = W[i];
    for (int i = t; i < NCLS; i += 256) sb[i] = b[i];
    int node0 = blockIdx.x * 8;
    for (int i = t; i < 8 * HD; i += 256) {
        int nl = i >> 6, node = node0 + nl;
        sx[nl][i & 63] = (node < n) ? fused[(size_t)node * HD + (i & 63)] : 0.f;
    }
    __syncthreads();
    for (int idx = t; idx < 8 * NCLS; idx += 256) {
        int nl = idx / NCLS, o = idx - nl * NCLS;
        int node = node0 + nl;
        if (node < n) {
            float acc = sb[o];
#pragma unroll
            for (int k = 0; k < HD; ++k) acc += sx[nl][k] * sW[k * NCLS + o];
            out[(size_t)node * NCLS + o] = acc;
        }
    }
}

extern "C" void kernel_launch(void* const* d_in, const int* in_sizes, int n_in,
                              void* d_out, int out_size, void* d_ws, size_t ws_size,
                              hipStream_t stream) {
    (void)in_sizes; (void)n_in; (void)out_size; (void)ws_size;
    const int N = NN, E = NE;

    const float* nf = (const float*)d_in[0];
    const int* srcs[2] = {(const int*)d_in[1], (const int*)d_in[3]};
    const int* dsts[2] = {(const int*)d_in[2], (const int*)d_in[4]};
    const float *W1[2], *b1[2], *g1[2], *bt1[2], *W2[2], *b2[2], *g2[2], *bt2[2];
    for (int br = 0; br < 2; ++br) {
        int base = 5 + br * 8;
        W1[br] = (const float*)d_in[base + 0];
        b1[br] = (const float*)d_in[base + 1];
        g1[br] = (const float*)d_in[base + 2];
        bt1[br] = (const float*)d_in[base + 3];
        W2[br] = (const float*)d_in[base + 4];
        b2[br] = (const float*)d_in[base + 5];
        g2[br] = (const float*)d_in[base + 6];
        bt2[br] = (const float*)d_in[base + 7];
    }
    const float* gW1 = (const float*)d_in[21];
    const float* gb1 = (const float*)d_in[22];
    const float* pa  = (const float*)d_in[23];
    const float* gW2 = (const float*)d_in[24];
    const float* gb2 = (const float*)d_in[25];
    const float* fcW = (const float*)d_in[26];
    const float* fcb = (const float*)d_in[27];
    float* out = (float*)d_out;

    // scratch carve (ws): ~54 MB
    char* p = (char*)d_ws;
    auto take = [&](size_t bytes) { char* r = p; p += (bytes + 255) & ~(size_t)255; return r; };
    size_t NH = (size_t)N * HD;
    float* H1 = (float*)take(NH * 4);
    float* H2 = (float*)take(NH * 4);
    float* ns = (float*)take((size_t)N * 4);
    float* nd = (float*)take((size_t)N * 4);
    float* stats = (float*)take(512);
    int* dego = (int*)take((size_t)N * 4);
    int* degi = (int*)take((size_t)N * 4);
    int* cursor = (int*)take((size_t)N * 4);
    int* rowptr = (int*)take((size_t)(N + 1) * 4);
    int* bsums = (int*)take(4096);
    // carve from d_out (dead until final FC): A = branch-1 output, col = CSR adjacency
    float* A = (float*)d_out;                       // N*64 f32 = 25.6MB
    int* col = (int*)((char*)d_out + NH * 4);       // E ints = 5MB (total 30.6 <= 51.6MB)

    int gE = (E + 255) / 256;
    int gN = (N + 255) / 256;
    int nScanBlk = (N + 1023) / 1024;

    for (int br = 0; br < 2; ++br) {
        hipMemsetAsync(dego, 0, (size_t)N * 4, stream);
        hipMemsetAsync(degi, 0, (size_t)N * 4, stream);
        k_deg<<<gE, 256, 0, stream>>>(srcs[br], dsts[br], dego, degi, E);
        k_norms<<<gN, 256, 0, stream>>>(dego, degi, ns, nd, N);
        k_scan_local<<<nScanBlk, 1024, 0, stream>>>(degi, rowptr, bsums, N);
        k_scan_tops<<<1, 1024, 0, stream>>>(bsums, nScanBlk);
        k_scan_add<<<gN, 256, 0, stream>>>(rowptr, bsums, N, E);
        hipMemsetAsync(cursor, 0, (size_t)N * 4, stream);
        k_csr_fill<<<gE, 256, 0, stream>>>(srcs[br], dsts[br], rowptr, cursor, col, E);

        float* l1out = H1;
        float* l2out = (br == 0) ? A : H2;

        k_gather<<<(N * 64) / 256, 256, 0, stream>>>(nf, ns, rowptr, col, l1out, N);
        hipMemsetAsync(stats, 0, 512, stream);
        k_lin_elu_stats<<<(N + 31) / 32, 256, 0, stream>>>(l1out, nd, W1[br], b1[br], stats, N);
        k_bn<<<(N * 16) / 256, 256, 0, stream>>>(l1out, stats, g1[br], bt1[br], N);

        k_gather<<<(N * 64) / 256, 256, 0, stream>>>(l1out, ns, rowptr, col, l2out, N);
        hipMemsetAsync(stats, 0, 512, stream);
        k_lin_elu_stats<<<(N + 31) / 32, 256, 0, stream>>>(l2out, nd, W2[br], b2[br], stats, N);
        k_bn<<<(N * 16) / 256, 256, 0, stream>>>(l2out, stats, g2[br], bt2[br], N);
    }

    k_comb1<<<(N + 31) / 32, 256, 0, stream>>>(A, H2, gW1, gb1, pa, H1, N);
    k_comb2<<<(N + 31) / 32, 256, 0, stream>>>(H1, A, H2, gW2, gb2, N);
    k_fc<<<(N + 7) / 8, 256, 0, stream>>>(H1, fcW, fcb, out, N);
}

// Round 2
// 1068.355 us; speedup vs baseline: 1.7189x; 1.7189x over previous
//
#include <hip/hip_runtime.h>
#include <math.h>

#define NN 100000
#define NE 1250000
#define HD 64
#define NCLS 129
#define NTILES 6250      // NN / 16
#define GRID_T 782       // 3128 waves -> ~2 tiles each

typedef float f32x4 __attribute__((ext_vector_type(4)));
typedef short bf16x8 __attribute__((ext_vector_type(8)));

__device__ __forceinline__ short f2b(float f) {
    unsigned u = __builtin_bit_cast(unsigned, f);
    u += 0x7FFFu + ((u >> 16) & 1u);
    return (short)(u >> 16);
}
__device__ __forceinline__ float b2f(short s) {
    return __builtin_bit_cast(float, ((unsigned)(unsigned short)s) << 16);
}

// ---------------- degree / norm ----------------
__global__ void k_deg(const int* __restrict__ src, const int* __restrict__ dst,
                      int* __restrict__ dego, int* __restrict__ degi, int e) {
    int i = blockIdx.x * blockDim.x + threadIdx.x;
    if (i < e) {
        atomicAdd(&dego[src[i]], 1);
        atomicAdd(&degi[dst[i]], 1);
    }
}

__global__ void k_norms(const int* __restrict__ dego, const int* __restrict__ degi,
                        float* __restrict__ ns, float* __restrict__ nd, int n) {
    int i = blockIdx.x * blockDim.x + threadIdx.x;
    if (i < n) {
        int a = dego[i]; if (a < 1) a = 1;
        int b = degi[i]; if (b < 1) b = 1;
        ns[i] = rsqrtf((float)a);
        nd[i] = rsqrtf((float)b);
    }
}

// ---------------- prefix scan (3-phase) ----------------
__global__ void k_scan_local(const int* __restrict__ deg, int* __restrict__ excl,
                             int* __restrict__ bsums, int n) {
    __shared__ int sm[1024];
    int t = threadIdx.x;
    int i = blockIdx.x * 1024 + t;
    int v = (i < n) ? deg[i] : 0;
    sm[t] = v;
    __syncthreads();
    for (int ofs = 1; ofs < 1024; ofs <<= 1) {
        int x = (t >= ofs) ? sm[t - ofs] : 0;
        __syncthreads();
        sm[t] += x;
        __syncthreads();
    }
    if (i < n) excl[i] = sm[t] - v;
    if (t == 1023) bsums[blockIdx.x] = sm[1023];
}

__global__ void k_scan_tops(int* __restrict__ bsums, int nb) {
    __shared__ int sm[1024];
    int t = threadIdx.x;
    int v = (t < nb) ? bsums[t] : 0;
    sm[t] = v;
    __syncthreads();
    for (int ofs = 1; ofs < 1024; ofs <<= 1) {
        int x = (t >= ofs) ? sm[t - ofs] : 0;
        __syncthreads();
        sm[t] += x;
        __syncthreads();
    }
    if (t < nb) bsums[t] = sm[t] - v;  // exclusive
}

__global__ void k_scan_add(int* __restrict__ excl, const int* __restrict__ bsums,
                           int n, int total) {
    int i = blockIdx.x * blockDim.x + threadIdx.x;
    if (i < n) excl[i] += bsums[i >> 10];
    if (i == 0) excl[n] = total;
}

__global__ void k_csr_fill(const int* __restrict__ src, const int* __restrict__ dst,
                           const int* __restrict__ rowptr, int* __restrict__ cursor,
                           int* __restrict__ col, int e) {
    int i = blockIdx.x * blockDim.x + threadIdx.x;
    if (i < e) {
        int d = dst[i];
        int p = atomicAdd(&cursor[d], 1);
        col[rowptr[d] + p] = src[i];
    }
}

// ---------------- prescale node_features by ns -> bf16 table ----------------
__global__ void k_scale_nf(const float* __restrict__ nf, const float* __restrict__ ns,
                           short* __restrict__ T) {
    int i = blockIdx.x * blockDim.x + threadIdx.x;  // NN*8 threads, 8 elems each
    if (i >= NN * 8) return;
    int node = i >> 3;
    float s = ns[node];
    const float4* p = (const float4*)(nf + (size_t)i * 8);
    float4 a = p[0], b = p[1];
    short r[8];
    r[0] = f2b(a.x * s); r[1] = f2b(a.y * s); r[2] = f2b(a.z * s); r[3] = f2b(a.w * s);
    r[4] = f2b(b.x * s); r[5] = f2b(b.y * s); r[6] = f2b(b.z * s); r[7] = f2b(b.w * s);
    *(bf16x8*)(T + (size_t)i * 8) = *(bf16x8*)r;
}

// ---------------- gather: out[w] = nd[w] * sum_{c in N(w)} tab[c]  (tab pre-scaled by ns)
__global__ __launch_bounds__(256) void k_gather(
    const short* __restrict__ tab, const float* __restrict__ nd,
    const int* __restrict__ rowptr, const int* __restrict__ col,
    short* __restrict__ out) {
    int w = (blockIdx.x * 256 + threadIdx.x) >> 6;
    int lane = threadIdx.x & 63;
    if (w >= NN) return;
    int beg = rowptr[w], end = rowptr[w + 1];
    float s = 0.f;
    for (int e = beg; e < end; ++e) {
        int c = col[e];
        s += b2f(tab[(size_t)c * HD + lane]);
    }
    out[(size_t)w * HD + lane] = f2b(s * nd[w]);
}

// ---------------- MFMA linear 64->64 + bias + ELU + column stats ----------------
__global__ __launch_bounds__(256) void k_lin(
    const short* __restrict__ X, const float* __restrict__ W,
    const float* __restrict__ bias, short* __restrict__ Y,
    float* __restrict__ stats) {
    __shared__ short sW[4096];
    __shared__ float sm2[128];
    int t = threadIdx.x;
    for (int i = t; i < 4096; i += 256) {
        int j = i & 7, l16i = (i >> 3) & 15, kgi = (i >> 7) & 3, kbi = (i >> 9) & 1, oti = (i >> 10) & 3;
        sW[i] = f2b(W[(kbi * 32 + kgi * 8 + j) * HD + oti * 16 + l16i]);
    }
    if (t < 128) sm2[t] = 0.f;
    __syncthreads();
    int lane = t & 63, wv = t >> 6, l16 = lane & 15, kg = lane >> 4;
    bf16x8 bfrag[2][4];
#pragma unroll
    for (int kb = 0; kb < 2; ++kb)
#pragma unroll
        for (int ot = 0; ot < 4; ++ot)
            bfrag[kb][ot] = *(const bf16x8*)&sW[((ot * 2 + kb) * 4 + kg) * 128 + l16 * 8];
    float bo[4];
#pragma unroll
    for (int ot = 0; ot < 4; ++ot) bo[ot] = bias[ot * 16 + l16];
    float ps[4] = {0.f, 0.f, 0.f, 0.f}, pq[4] = {0.f, 0.f, 0.f, 0.f};
    for (int tile = blockIdx.x * 4 + wv; tile < NTILES; tile += GRID_T * 4) {
        const short* xp = X + ((size_t)tile * 16 + l16) * HD + kg * 8;
        bf16x8 a0 = *(const bf16x8*)xp;
        bf16x8 a1 = *(const bf16x8*)(xp + 32);
        f32x4 acc[4];
#pragma unroll
        for (int ot = 0; ot < 4; ++ot) {
            acc[ot] = (f32x4){0.f, 0.f, 0.f, 0.f};
            acc[ot] = __builtin_amdgcn_mfma_f32_16x16x32_bf16(a0, bfrag[0][ot], acc[ot], 0, 0, 0);
            acc[ot] = __builtin_amdgcn_mfma_f32_16x16x32_bf16(a1, bfrag[1][ot], acc[ot], 0, 0, 0);
        }
#pragma unroll
        for (int ot = 0; ot < 4; ++ot) {
#pragma unroll
            for (int r = 0; r < 4; ++r) {
                float y = acc[ot][r] + bo[ot];
                y = y > 0.f ? y : expm1f(y);
                ps[ot] += y; pq[ot] += y * y;
                Y[((size_t)tile * 16 + kg * 4 + r) * HD + ot * 16 + l16] = f2b(y);
            }
        }
    }
#pragma unroll
    for (int ot = 0; ot < 4; ++ot) {
        atomicAdd(&sm2[ot * 16 + l16], ps[ot]);
        atomicAdd(&sm2[64 + ot * 16 + l16], pq[ot]);
    }
    __syncthreads();
    if (t < 128) atomicAdd(&stats[t], sm2[t]);
}

// ---------------- BN apply (bf16 in/out), optional ns fold ----------------
__global__ void k_bnb(const short* __restrict__ Y, short* __restrict__ O,
                      const float* __restrict__ stats, const float* __restrict__ g,
                      const float* __restrict__ bt, const float* __restrict__ ns) {
    int i = blockIdx.x * blockDim.x + threadIdx.x;  // NN*8 threads
    if (i >= NN * 8) return;
    int node = i >> 3;
    int o0 = (i & 7) * 8;
    float extra = ns ? ns[node] : 1.f;
    bf16x8 v = *(const bf16x8*)(Y + (size_t)i * 8);
    short r[8];
    const float invN = 1.f / (float)NN;
#pragma unroll
    for (int j = 0; j < 8; ++j) {
        int o = o0 + j;
        float mu = stats[o] * invN;
        float var = fmaxf(stats[64 + o] * invN - mu * mu, 0.f);
        float isd = rsqrtf(var + 1e-5f);
        float sc = g[o] * isd * extra;
        float sh = (bt[o] - mu * g[o] * isd) * extra;
        r[j] = f2b(b2f(v[j]) * sc + sh);
    }
    *(bf16x8*)(O + (size_t)i * 8) = *(bf16x8*)r;
}

// ---------------- comb1: Z = PReLU(cat(h1,h2,|h1-h2|,h1*h2) @ gW1 + gb1) ----------------
__global__ __launch_bounds__(256) void k_comb1(
    const short* __restrict__ H1, const short* __restrict__ H2,
    const float* __restrict__ W, const float* __restrict__ bias,
    const float* __restrict__ pa, short* __restrict__ Z) {
    __shared__ short sW[16384];
    int t = threadIdx.x;
    for (int i = t; i < 16384; i += 256) {
        int j = i & 7, l16i = (i >> 3) & 15, kgi = (i >> 7) & 3, kbi = (i >> 9) & 7, oti = (i >> 12) & 3;
        sW[i] = f2b(W[(kbi * 32 + kgi * 8 + j) * HD + oti * 16 + l16i]);
    }
    __syncthreads();
    int lane = t & 63, wv = t >> 6, l16 = lane & 15, kg = lane >> 4;
    float slope = pa[0];
    float bo[4];
#pragma unroll
    for (int ot = 0; ot < 4; ++ot) bo[ot] = bias[ot * 16 + l16];
    for (int tile = blockIdx.x * 4 + wv; tile < NTILES; tile += GRID_T * 4) {
        size_t rb = ((size_t)tile * 16 + l16) * HD + kg * 8;
        bf16x8 h1e = *(const bf16x8*)(H1 + rb);
        bf16x8 h1o = *(const bf16x8*)(H1 + rb + 32);
        bf16x8 h2e = *(const bf16x8*)(H2 + rb);
        bf16x8 h2o = *(const bf16x8*)(H2 + rb + 32);
        bf16x8 fe[8];
        fe[0] = h1e; fe[1] = h1o; fe[2] = h2e; fe[3] = h2o;
        short tabs[8], tprd[8];
#pragma unroll
        for (int j = 0; j < 8; ++j) {
            float a = b2f(h1e[j]), b = b2f(h2e[j]);
            tabs[j] = f2b(fabsf(a - b)); tprd[j] = f2b(a * b);
        }
        fe[4] = *(bf16x8*)tabs; fe[6] = *(bf16x8*)tprd;
#pragma unroll
        for (int j = 0; j < 8; ++j) {
            float a = b2f(h1o[j]), b = b2f(h2o[j]);
            tabs[j] = f2b(fabsf(a - b)); tprd[j] = f2b(a * b);
        }
        fe[5] = *(bf16x8*)tabs; fe[7] = *(bf16x8*)tprd;
        f32x4 acc[4];
#pragma unroll
        for (int ot = 0; ot < 4; ++ot) acc[ot] = (f32x4){0.f, 0.f, 0.f, 0.f};
#pragma unroll
        for (int kb = 0; kb < 8; ++kb)
#pragma unroll
            for (int ot = 0; ot < 4; ++ot) {
                bf16x8 bf = *(const bf16x8*)&sW[((ot * 8 + kb) * 4 + kg) * 128 + l16 * 8];
                acc[ot] = __builtin_amdgcn_mfma_f32_16x16x32_bf16(fe[kb], bf, acc[ot], 0, 0, 0);
            }
#pragma unroll
        for (int ot = 0; ot < 4; ++ot)
#pragma unroll
            for (int r = 0; r < 4; ++r) {
                float z = acc[ot][r] + bo[ot];
                z = z > 0.f ? z : slope * z;
                Z[((size_t)tile * 16 + kg * 4 + r) * HD + ot * 16 + l16] = f2b(z);
            }
    }
}

// ---------------- comb2: gate = sigmoid(Z @ gW2 + gb2) ----------------
__global__ __launch_bounds__(256) void k_comb2(
    const short* __restrict__ Z, const float* __restrict__ W,
    const float* __restrict__ bias, short* __restrict__ G) {
    __shared__ short sW[4096];
    int t = threadIdx.x;
    for (int i = t; i < 4096; i += 256) {
        int j = i & 7, l16i = (i >> 3) & 15, kgi = (i >> 7) & 3, kbi = (i >> 9) & 1, oti = (i >> 10) & 3;
        sW[i] = f2b(W[(kbi * 32 + kgi * 8 + j) * HD + oti * 16 + l16i]);
    }
    __syncthreads();
    int lane = t & 63, wv = t >> 6, l16 = lane & 15, kg = lane >> 4;
    bf16x8 bfrag[2][4];
#pragma unroll
    for (int kb = 0; kb < 2; ++kb)
#pragma unroll
        for (int ot = 0; ot < 4; ++ot)
            bfrag[kb][ot] = *(const bf16x8*)&sW[((ot * 2 + kb) * 4 + kg) * 128 + l16 * 8];
    float bo[4];
#pragma unroll
    for (int ot = 0; ot < 4; ++ot) bo[ot] = bias[ot * 16 + l16];
    for (int tile = blockIdx.x * 4 + wv; tile < NTILES; tile += GRID_T * 4) {
        const short* xp = Z + ((size_t)tile * 16 + l16) * HD + kg * 8;
        bf16x8 a0 = *(const bf16x8*)xp;
        bf16x8 a1 = *(const bf16x8*)(xp + 32);
        f32x4 acc[4];
#pragma unroll
        for (int ot = 0; ot < 4; ++ot) {
            acc[ot] = (f32x4){0.f, 0.f, 0.f, 0.f};
            acc[ot] = __builtin_amdgcn_mfma_f32_16x16x32_bf16(a0, bfrag[0][ot], acc[ot], 0, 0, 0);
            acc[ot] = __builtin_amdgcn_mfma_f32_16x16x32_bf16(a1, bfrag[1][ot], acc[ot], 0, 0, 0);
        }
#pragma unroll
        for (int ot = 0; ot < 4; ++ot)
#pragma unroll
            for (int r = 0; r < 4; ++r) {
                float y = acc[ot][r] + bo[ot];
                float gate = 1.f / (1.f + expf(-y));
                G[((size_t)tile * 16 + kg * 4 + r) * HD + ot * 16 + l16] = f2b(gate);
            }
    }
}

// ---------------- fc: out = (g*h1 + (1-g)*h2) @ fcW + fcb ----------------
__global__ __launch_bounds__(256) void k_fc(
    const short* __restrict__ G, const short* __restrict__ H1, const short* __restrict__ H2,
    const float* __restrict__ W, const float* __restrict__ bias,
    float* __restrict__ out) {
    __shared__ short sW[9216];  // 9 ot-tiles x 64 k (cols 129 padded to 144)
    int t = threadIdx.x;
    for (int i = t; i < 9216; i += 256) {
        int j = i & 7, l16i = (i >> 3) & 15, kgi = (i >> 7) & 3, kbi = (i >> 9) & 1, oti = i >> 10;
        int k = kbi * 32 + kgi * 8 + j, o = oti * 16 + l16i;
        sW[i] = (o < NCLS) ? f2b(W[k * NCLS + o]) : (short)0;
    }
    __syncthreads();
    int lane = t & 63, wv = t >> 6, l16 = lane & 15, kg = lane >> 4;
    float bo[9];
#pragma unroll
    for (int ot = 0; ot < 9; ++ot) {
        int o = ot * 16 + l16;
        bo[ot] = (o < NCLS) ? bias[o] : 0.f;
    }
    for (int tile = blockIdx.x * 4 + wv; tile < NTILES; tile += GRID_T * 4) {
        size_t rb = ((size_t)tile * 16 + l16) * HD;
        f32x4 acc[9];
#pragma unroll
        for (int ot = 0; ot < 9; ++ot) acc[ot] = (f32x4){0.f, 0.f, 0.f, 0.f};
#pragma unroll
        for (int kb = 0; kb < 2; ++kb) {
            int koff = kb * 32 + kg * 8;
            bf16x8 gv  = *(const bf16x8*)(G + rb + koff);
            bf16x8 h1v = *(const bf16x8*)(H1 + rb + koff);
            bf16x8 h2v = *(const bf16x8*)(H2 + rb + koff);
            short af[8];
#pragma unroll
            for (int j = 0; j < 8; ++j) {
                float gf = b2f(gv[j]);
                af[j] = f2b(gf * b2f(h1v[j]) + (1.f - gf) * b2f(h2v[j]));
            }
            bf16x8 a = *(bf16x8*)af;
#pragma unroll
            for (int ot = 0; ot < 9; ++ot) {
                bf16x8 bf = *(const bf16x8*)&sW[((ot * 2 + kb) * 4 + kg) * 128 + l16 * 8];
                acc[ot] = __builtin_amdgcn_mfma_f32_16x16x32_bf16(a, bf, acc[ot], 0, 0, 0);
            }
        }
#pragma unroll
        for (int ot = 0; ot < 9; ++ot) {
            int o = ot * 16 + l16;
            if (o < NCLS) {
#pragma unroll
                for (int r = 0; r < 4; ++r) {
                    int node = tile * 16 + kg * 4 + r;
                    out[(size_t)node * NCLS + o] = acc[ot][r] + bo[ot];
                }
            }
        }
    }
}

extern "C" void kernel_launch(void* const* d_in, const int* in_sizes, int n_in,
                              void* d_out, int out_size, void* d_ws, size_t ws_size,
                              hipStream_t stream) {
    (void)in_sizes; (void)n_in; (void)out_size; (void)ws_size;
    const int N = NN, E = NE;

    const float* nf = (const float*)d_in[0];
    const int* srcs[2] = {(const int*)d_in[1], (const int*)d_in[3]};
    const int* dsts[2] = {(const int*)d_in[2], (const int*)d_in[4]};
    const float *W1[2], *b1[2], *g1[2], *bt1[2], *W2[2], *b2[2], *g2[2], *bt2[2];
    for (int br = 0; br < 2; ++br) {
        int base = 5 + br * 8;
        W1[br] = (const float*)d_in[base + 0];
        b1[br] = (const float*)d_in[base + 1];
        g1[br] = (const float*)d_in[base + 2];
        bt1[br] = (const float*)d_in[base + 3];
        W2[br] = (const float*)d_in[base + 4];
        b2[br] = (const float*)d_in[base + 5];
        g2[br] = (const float*)d_in[base + 6];
        bt2[br] = (const float*)d_in[base + 7];
    }
    const float* gW1 = (const float*)d_in[21];
    const float* gb1 = (const float*)d_in[22];
    const float* pa  = (const float*)d_in[23];
    const float* gW2 = (const float*)d_in[24];
    const float* gb2 = (const float*)d_in[25];
    const float* fcW = (const float*)d_in[26];
    const float* fcb = (const float*)d_in[27];
    float* out = (float*)d_out;

    // ws carve (~54 MB)
    char* p = (char*)d_ws;
    auto take = [&](size_t bytes) { char* r = p; p += (bytes + 255) & ~(size_t)255; return r; };
    size_t NHb = (size_t)N * HD * 2;  // bf16 table bytes
    short* X    = (short*)take(NHb);
    short* Yraw = (short*)take(NHb);
    short* Hbn[2];
    Hbn[0] = (short*)take(NHb);
    Hbn[1] = (short*)take(NHb);
    float* ns = (float*)take((size_t)N * 4);
    float* nd = (float*)take((size_t)N * 4);
    float* stats = (float*)take(512);
    int* dego = (int*)take((size_t)N * 4);
    int* degi = (int*)take((size_t)N * 4);
    int* cursor = (int*)take((size_t)N * 4);
    int* rowptr = (int*)take((size_t)(N + 1) * 4);
    int* bsums = (int*)take(4096);
    // carve from d_out (dead until k_fc): Z (12.8MB) + col (5MB)
    short* Z = (short*)d_out;
    int* col = (int*)((char*)d_out + NHb);

    int gE = (E + 255) / 256;
    int gN = (N + 255) / 256;
    int nScanBlk = (N + 1023) / 1024;
    int gEW = (N * 8 + 255) / 256;  // elementwise over N*8

    for (int br = 0; br < 2; ++br) {
        hipMemsetAsync(dego, 0, (size_t)N * 4, stream);
        hipMemsetAsync(degi, 0, (size_t)N * 4, stream);
        k_deg<<<gE, 256, 0, stream>>>(srcs[br], dsts[br], dego, degi, E);
        k_norms<<<gN, 256, 0, stream>>>(dego, degi, ns, nd, N);
        k_scan_local<<<nScanBlk, 1024, 0, stream>>>(degi, rowptr, bsums, N);
        k_scan_tops<<<1, 1024, 0, stream>>>(bsums, nScanBlk);
        k_scan_add<<<gN, 256, 0, stream>>>(rowptr, bsums, N, E);
        hipMemsetAsync(cursor, 0, (size_t)N * 4, stream);
        k_csr_fill<<<gE, 256, 0, stream>>>(srcs[br], dsts[br], rowptr, cursor, col, E);

        // layer 1
        k_scale_nf<<<gEW, 256, 0, stream>>>(nf, ns, Yraw);          // Yraw <- bf16(nf*ns)
        k_gather<<<(N * 64) / 256, 256, 0, stream>>>(Yraw, nd, rowptr, col, X);
        hipMemsetAsync(stats, 0, 512, stream);
        k_lin<<<GRID_T, 256, 0, stream>>>(X, W1[br], b1[br], Yraw, stats);
        k_bnb<<<gEW, 256, 0, stream>>>(Yraw, Hbn[br], stats, g1[br], bt1[br], ns);  // temp, ns-folded

        // layer 2
        k_gather<<<(N * 64) / 256, 256, 0, stream>>>(Hbn[br], nd, rowptr, col, X);
        hipMemsetAsync(stats, 0, 512, stream);
        k_lin<<<GRID_T, 256, 0, stream>>>(X, W2[br], b2[br], Yraw, stats);
        k_bnb<<<gEW, 256, 0, stream>>>(Yraw, Hbn[br], stats, g2[br], bt2[br], (const float*)nullptr);
    }

    k_comb1<<<GRID_T, 256, 0, stream>>>(Hbn[0], Hbn[1], gW1, gb1, pa, Z);
    k_comb2<<<GRID_T, 256, 0, stream>>>(Z, gW2, gb2, X);             // X = gate
    k_fc<<<GRID_T, 256, 0, stream>>>(X, Hbn[0], Hbn[1], fcW, fcb, out);
}

// Round 3
// 794.681 us; speedup vs baseline: 2.3109x; 1.3444x over previous
//
#include <hip/hip_runtime.h>
#include <math.h>

#define NN 100000
#define NE 1250000
#define HD 64
#define NCLS 129
#define NTILES 6250      // NN / 16
#define GRID_T 782       // 3128 waves -> ~2 tiles each

typedef float f32x4 __attribute__((ext_vector_type(4)));
typedef short bf16x8 __attribute__((ext_vector_type(8)));

__device__ __forceinline__ short f2b(float f) {
    unsigned u = __builtin_bit_cast(unsigned, f);
    u += 0x7FFFu + ((u >> 16) & 1u);
    return (short)(u >> 16);
}
__device__ __forceinline__ float b2f(short s) {
    return __builtin_bit_cast(float, ((unsigned)(unsigned short)s) << 16);
}

// ---------------- degree / norm ----------------
__global__ void k_deg(const int* __restrict__ src, const int* __restrict__ dst,
                      int* __restrict__ dego, int* __restrict__ degi, int e) {
    int i = blockIdx.x * blockDim.x + threadIdx.x;
    if (i < e) {
        atomicAdd(&dego[src[i]], 1);
        atomicAdd(&degi[dst[i]], 1);
    }
}

__global__ void k_norms(const int* __restrict__ dego, const int* __restrict__ degi,
                        float* __restrict__ ns, float* __restrict__ nd, int n) {
    int i = blockIdx.x * blockDim.x + threadIdx.x;
    if (i < n) {
        int a = dego[i]; if (a < 1) a = 1;
        int b = degi[i]; if (b < 1) b = 1;
        ns[i] = rsqrtf((float)a);
        nd[i] = rsqrtf((float)b);
    }
}

// ---------------- prefix scan (3-phase) ----------------
__global__ void k_scan_local(const int* __restrict__ deg, int* __restrict__ excl,
                             int* __restrict__ bsums, int n) {
    __shared__ int sm[1024];
    int t = threadIdx.x;
    int i = blockIdx.x * 1024 + t;
    int v = (i < n) ? deg[i] : 0;
    sm[t] = v;
    __syncthreads();
    for (int ofs = 1; ofs < 1024; ofs <<= 1) {
        int x = (t >= ofs) ? sm[t - ofs] : 0;
        __syncthreads();
        sm[t] += x;
        __syncthreads();
    }
    if (i < n) excl[i] = sm[t] - v;
    if (t == 1023) bsums[blockIdx.x] = sm[1023];
}

__global__ void k_scan_tops(int* __restrict__ bsums, int nb) {
    __shared__ int sm[1024];
    int t = threadIdx.x;
    int v = (t < nb) ? bsums[t] : 0;
    sm[t] = v;
    __syncthreads();
    for (int ofs = 1; ofs < 1024; ofs <<= 1) {
        int x = (t >= ofs) ? sm[t - ofs] : 0;
        __syncthreads();
        sm[t] += x;
        __syncthreads();
    }
    if (t < nb) bsums[t] = sm[t] - v;  // exclusive
}

__global__ void k_scan_add(int* __restrict__ excl, const int* __restrict__ bsums,
                           int n, int total) {
    int i = blockIdx.x * blockDim.x + threadIdx.x;
    if (i < n) excl[i] += bsums[i >> 10];
    if (i == 0) excl[n] = total;
}

__global__ void k_csr_fill(const int* __restrict__ src, const int* __restrict__ dst,
                           const int* __restrict__ rowptr, int* __restrict__ cursor,
                           int* __restrict__ col, int e) {
    int i = blockIdx.x * blockDim.x + threadIdx.x;
    if (i < e) {
        int d = dst[i];
        int p = atomicAdd(&cursor[d], 1);
        col[rowptr[d] + p] = src[i];
    }
}

// ---------------- prescale node_features by ns -> bf16 table ----------------
__global__ void k_scale_nf(const float* __restrict__ nf, const float* __restrict__ ns,
                           short* __restrict__ T) {
    int i = blockIdx.x * blockDim.x + threadIdx.x;  // NN*8 threads, 8 elems each
    if (i >= NN * 8) return;
    int node = i >> 3;
    float s = ns[node];
    const float4* p = (const float4*)(nf + (size_t)i * 8);
    float4 a = p[0], b = p[1];
    short r[8];
    r[0] = f2b(a.x * s); r[1] = f2b(a.y * s); r[2] = f2b(a.z * s); r[3] = f2b(a.w * s);
    r[4] = f2b(b.x * s); r[5] = f2b(b.y * s); r[6] = f2b(b.z * s); r[7] = f2b(b.w * s);
    *(bf16x8*)(T + (size_t)i * 8) = *(bf16x8*)r;
}

// ---------------- gather: out[w] = nd[w] * sum_{c in N(w)} tab[c]  (tab pre-scaled by ns)
// cooperative col prefetch + 8-wide independent row loads for MLP
__global__ __launch_bounds__(256) void k_gather(
    const short* __restrict__ tab, const float* __restrict__ nd,
    const int* __restrict__ rowptr, const int* __restrict__ col,
    short* __restrict__ out) {
    int w = (blockIdx.x * 256 + threadIdx.x) >> 6;
    int lane = threadIdx.x & 63;
    if (w >= NN) return;
    int beg = rowptr[w], end = rowptr[w + 1];
    float s = 0.f;
    for (int e0 = beg; e0 < end; e0 += 64) {
        int cnt = end - e0; if (cnt > 64) cnt = 64;
        int myc = (lane < cnt) ? col[e0 + lane] : 0;
        for (int j = 0; j < cnt; j += 8) {
#pragma unroll
            for (int u = 0; u < 8; ++u) {
                int c = __shfl(myc, j + u, 64);
                float v = b2f(tab[(size_t)c * HD + lane]);
                s += (j + u < cnt) ? v : 0.f;
            }
        }
    }
    out[(size_t)w * HD + lane] = f2b(s * nd[w]);
}

// ---------------- MFMA linear 64->64 + bias + ELU + column stats ----------------
__global__ __launch_bounds__(256) void k_lin(
    const short* __restrict__ X, const float* __restrict__ W,
    const float* __restrict__ bias, short* __restrict__ Y,
    float* __restrict__ stats) {
    __shared__ short sW[4096];
    __shared__ float sm2[128];
    int t = threadIdx.x;
    for (int i = t; i < 4096; i += 256) {
        int j = i & 7, l16i = (i >> 3) & 15, kgi = (i >> 7) & 3, kbi = (i >> 9) & 1, oti = (i >> 10) & 3;
        sW[i] = f2b(W[(kbi * 32 + kgi * 8 + j) * HD + oti * 16 + l16i]);
    }
    if (t < 128) sm2[t] = 0.f;
    __syncthreads();
    int lane = t & 63, wv = t >> 6, l16 = lane & 15, kg = lane >> 4;
    bf16x8 bfrag[2][4];
#pragma unroll
    for (int kb = 0; kb < 2; ++kb)
#pragma unroll
        for (int ot = 0; ot < 4; ++ot)
            bfrag[kb][ot] = *(const bf16x8*)&sW[((ot * 2 + kb) * 4 + kg) * 128 + l16 * 8];
    float bo[4];
#pragma unroll
    for (int ot = 0; ot < 4; ++ot) bo[ot] = bias[ot * 16 + l16];
    float ps[4] = {0.f, 0.f, 0.f, 0.f}, pq[4] = {0.f, 0.f, 0.f, 0.f};
    for (int tile = blockIdx.x * 4 + wv; tile < NTILES; tile += GRID_T * 4) {
        const short* xp = X + ((size_t)tile * 16 + l16) * HD + kg * 8;
        bf16x8 a0 = *(const bf16x8*)xp;
        bf16x8 a1 = *(const bf16x8*)(xp + 32);
        f32x4 acc[4];
#pragma unroll
        for (int ot = 0; ot < 4; ++ot) {
            acc[ot] = (f32x4){0.f, 0.f, 0.f, 0.f};
            acc[ot] = __builtin_amdgcn_mfma_f32_16x16x32_bf16(a0, bfrag[0][ot], acc[ot], 0, 0, 0);
            acc[ot] = __builtin_amdgcn_mfma_f32_16x16x32_bf16(a1, bfrag[1][ot], acc[ot], 0, 0, 0);
        }
#pragma unroll
        for (int ot = 0; ot < 4; ++ot) {
#pragma unroll
            for (int r = 0; r < 4; ++r) {
                float y = acc[ot][r] + bo[ot];
                y = y > 0.f ? y : expm1f(y);
                ps[ot] += y; pq[ot] += y * y;
                Y[((size_t)tile * 16 + kg * 4 + r) * HD + ot * 16 + l16] = f2b(y);
            }
        }
    }
#pragma unroll
    for (int ot = 0; ot < 4; ++ot) {
        atomicAdd(&sm2[ot * 16 + l16], ps[ot]);
        atomicAdd(&sm2[64 + ot * 16 + l16], pq[ot]);
    }
    __syncthreads();
    if (t < 128) atomicAdd(&stats[t], sm2[t]);
}

// ---------------- BN apply (bf16 in/out), optional ns fold ----------------
__global__ void k_bnb(const short* __restrict__ Y, short* __restrict__ O,
                      const float* __restrict__ stats, const float* __restrict__ g,
                      const float* __restrict__ bt, const float* __restrict__ ns) {
    int i = blockIdx.x * blockDim.x + threadIdx.x;  // NN*8 threads
    if (i >= NN * 8) return;
    int node = i >> 3;
    int o0 = (i & 7) * 8;
    float extra = ns ? ns[node] : 1.f;
    bf16x8 v = *(const bf16x8*)(Y + (size_t)i * 8);
    short r[8];
    const float invN = 1.f / (float)NN;
#pragma unroll
    for (int j = 0; j < 8; ++j) {
        int o = o0 + j;
        float mu = stats[o] * invN;
        float var = fmaxf(stats[64 + o] * invN - mu * mu, 0.f);
        float isd = rsqrtf(var + 1e-5f);
        float sc = g[o] * isd * extra;
        float sh = (bt[o] - mu * g[o] * isd) * extra;
        r[j] = f2b(b2f(v[j]) * sc + sh);
    }
    *(bf16x8*)(O + (size_t)i * 8) = *(bf16x8*)r;
}

// ---------------- comb1: Z = PReLU(cat(h1,h2,|h1-h2|,h1*h2) @ gW1 + gb1) ----------------
__global__ __launch_bounds__(256) void k_comb1(
    const short* __restrict__ H1, const short* __restrict__ H2,
    const float* __restrict__ W, const float* __restrict__ bias,
    const float* __restrict__ pa, short* __restrict__ Z) {
    __shared__ short sW[16384];
    int t = threadIdx.x;
    for (int i = t; i < 16384; i += 256) {
        int j = i & 7, l16i = (i >> 3) & 15, kgi = (i >> 7) & 3, kbi = (i >> 9) & 7, oti = (i >> 12) & 3;
        sW[i] = f2b(W[(kbi * 32 + kgi * 8 + j) * HD + oti * 16 + l16i]);
    }
    __syncthreads();
    int lane = t & 63, wv = t >> 6, l16 = lane & 15, kg = lane >> 4;
    float slope = pa[0];
    float bo[4];
#pragma unroll
    for (int ot = 0; ot < 4; ++ot) bo[ot] = bias[ot * 16 + l16];
    for (int tile = blockIdx.x * 4 + wv; tile < NTILES; tile += GRID_T * 4) {
        size_t rb = ((size_t)tile * 16 + l16) * HD + kg * 8;
        bf16x8 h1e = *(const bf16x8*)(H1 + rb);
        bf16x8 h1o = *(const bf16x8*)(H1 + rb + 32);
        bf16x8 h2e = *(const bf16x8*)(H2 + rb);
        bf16x8 h2o = *(const bf16x8*)(H2 + rb + 32);
        bf16x8 fe[8];
        fe[0] = h1e; fe[1] = h1o; fe[2] = h2e; fe[3] = h2o;
        short tabs[8], tprd[8];
#pragma unroll
        for (int j = 0; j < 8; ++j) {
            float a = b2f(h1e[j]), b = b2f(h2e[j]);
            tabs[j] = f2b(fabsf(a - b)); tprd[j] = f2b(a * b);
        }
        fe[4] = *(bf16x8*)tabs; fe[6] = *(bf16x8*)tprd;
#pragma unroll
        for (int j = 0; j < 8; ++j) {
            float a = b2f(h1o[j]), b = b2f(h2o[j]);
            tabs[j] = f2b(fabsf(a - b)); tprd[j] = f2b(a * b);
        }
        fe[5] = *(bf16x8*)tabs; fe[7] = *(bf16x8*)tprd;
        f32x4 acc[4];
#pragma unroll
        for (int ot = 0; ot < 4; ++ot) acc[ot] = (f32x4){0.f, 0.f, 0.f, 0.f};
#pragma unroll
        for (int kb = 0; kb < 8; ++kb)
#pragma unroll
            for (int ot = 0; ot < 4; ++ot) {
                bf16x8 bf = *(const bf16x8*)&sW[((ot * 8 + kb) * 4 + kg) * 128 + l16 * 8];
                acc[ot] = __builtin_amdgcn_mfma_f32_16x16x32_bf16(fe[kb], bf, acc[ot], 0, 0, 0);
            }
#pragma unroll
        for (int ot = 0; ot < 4; ++ot)
#pragma unroll
            for (int r = 0; r < 4; ++r) {
                float z = acc[ot][r] + bo[ot];
                z = z > 0.f ? z : slope * z;
                Z[((size_t)tile * 16 + kg * 4 + r) * HD + ot * 16 + l16] = f2b(z);
            }
    }
}

// ---------------- comb2: gate = sigmoid(Z @ gW2 + gb2) ----------------
__global__ __launch_bounds__(256) void k_comb2(
    const short* __restrict__ Z, const float* __restrict__ W,
    const float* __restrict__ bias, short* __restrict__ G) {
    __shared__ short sW[4096];
    int t = threadIdx.x;
    for (int i = t; i < 4096; i += 256) {
        int j = i & 7, l16i = (i >> 3) & 15, kgi = (i >> 7) & 3, kbi = (i >> 9) & 1, oti = (i >> 10) & 3;
        sW[i] = f2b(W[(kbi * 32 + kgi * 8 + j) * HD + oti * 16 + l16i]);
    }
    __syncthreads();
    int lane = t & 63, wv = t >> 6, l16 = lane & 15, kg = lane >> 4;
    bf16x8 bfrag[2][4];
#pragma unroll
    for (int kb = 0; kb < 2; ++kb)
#pragma unroll
        for (int ot = 0; ot < 4; ++ot)
            bfrag[kb][ot] = *(const bf16x8*)&sW[((ot * 2 + kb) * 4 + kg) * 128 + l16 * 8];
    float bo[4];
#pragma unroll
    for (int ot = 0; ot < 4; ++ot) bo[ot] = bias[ot * 16 + l16];
    for (int tile = blockIdx.x * 4 + wv; tile < NTILES; tile += GRID_T * 4) {
        const short* xp = Z + ((size_t)tile * 16 + l16) * HD + kg * 8;
        bf16x8 a0 = *(const bf16x8*)xp;
        bf16x8 a1 = *(const bf16x8*)(xp + 32);
        f32x4 acc[4];
#pragma unroll
        for (int ot = 0; ot < 4; ++ot) {
            acc[ot] = (f32x4){0.f, 0.f, 0.f, 0.f};
            acc[ot] = __builtin_amdgcn_mfma_f32_16x16x32_bf16(a0, bfrag[0][ot], acc[ot], 0, 0, 0);
            acc[ot] = __builtin_amdgcn_mfma_f32_16x16x32_bf16(a1, bfrag[1][ot], acc[ot], 0, 0, 0);
        }
#pragma unroll
        for (int ot = 0; ot < 4; ++ot)
#pragma unroll
            for (int r = 0; r < 4; ++r) {
                float y = acc[ot][r] + bo[ot];
                float gate = 1.f / (1.f + expf(-y));
                G[((size_t)tile * 16 + kg * 4 + r) * HD + ot * 16 + l16] = f2b(gate);
            }
    }
}

// ---------------- fc: out = (g*h1 + (1-g)*h2) @ fcW + fcb ----------------
__global__ __launch_bounds__(256) void k_fc(
    const short* __restrict__ G, const short* __restrict__ H1, const short* __restrict__ H2,
    const float* __restrict__ W, const float* __restrict__ bias,
    float* __restrict__ out) {
    __shared__ short sW[9216];  // 9 ot-tiles x 64 k (cols 129 padded to 144)
    int t = threadIdx.x;
    for (int i = t; i < 9216; i += 256) {
        int j = i & 7, l16i = (i >> 3) & 15, kgi = (i >> 7) & 3, kbi = (i >> 9) & 1, oti = i >> 10;
        int k = kbi * 32 + kgi * 8 + j, o = oti * 16 + l16i;
        sW[i] = (o < NCLS) ? f2b(W[k * NCLS + o]) : (short)0;
    }
    __syncthreads();
    int lane = t & 63, wv = t >> 6, l16 = lane & 15, kg = lane >> 4;
    float bo[9];
#pragma unroll
    for (int ot = 0; ot < 9; ++ot) {
        int o = ot * 16 + l16;
        bo[ot] = (o < NCLS) ? bias[o] : 0.f;
    }
    for (int tile = blockIdx.x * 4 + wv; tile < NTILES; tile += GRID_T * 4) {
        size_t rb = ((size_t)tile * 16 + l16) * HD;
        f32x4 acc[9];
#pragma unroll
        for (int ot = 0; ot < 9; ++ot) acc[ot] = (f32x4){0.f, 0.f, 0.f, 0.f};
#pragma unroll
        for (int kb = 0; kb < 2; ++kb) {
            int koff = kb * 32 + kg * 8;
            bf16x8 gv  = *(const bf16x8*)(G + rb + koff);
            bf16x8 h1v = *(const bf16x8*)(H1 + rb + koff);
            bf16x8 h2v = *(const bf16x8*)(H2 + rb + koff);
            short af[8];
#pragma unroll
            for (int j = 0; j < 8; ++j) {
                float gf = b2f(gv[j]);
                af[j] = f2b(gf * b2f(h1v[j]) + (1.f - gf) * b2f(h2v[j]));
            }
            bf16x8 a = *(bf16x8*)af;
#pragma unroll
            for (int ot = 0; ot < 9; ++ot) {
                bf16x8 bf = *(const bf16x8*)&sW[((ot * 2 + kb) * 4 + kg) * 128 + l16 * 8];
                acc[ot] = __builtin_amdgcn_mfma_f32_16x16x32_bf16(a, bf, acc[ot], 0, 0, 0);
            }
        }
#pragma unroll
        for (int ot = 0; ot < 9; ++ot) {
            int o = ot * 16 + l16;
            if (o < NCLS) {
#pragma unroll
                for (int r = 0; r < 4; ++r) {
                    int node = tile * 16 + kg * 4 + r;
                    out[(size_t)node * NCLS + o] = acc[ot][r] + bo[ot];
                }
            }
        }
    }
}

extern "C" void kernel_launch(void* const* d_in, const int* in_sizes, int n_in,
                              void* d_out, int out_size, void* d_ws, size_t ws_size,
                              hipStream_t stream) {
    (void)in_sizes; (void)n_in; (void)out_size; (void)ws_size;
    const int N = NN, E = NE;

    const float* nf = (const float*)d_in[0];
    const int* srcs[2] = {(const int*)d_in[1], (const int*)d_in[3]};
    const int* dsts[2] = {(const int*)d_in[2], (const int*)d_in[4]};
    const float *W1[2], *b1[2], *g1[2], *bt1[2], *W2[2], *b2[2], *g2[2], *bt2[2];
    for (int br = 0; br < 2; ++br) {
        int base = 5 + br * 8;
        W1[br] = (const float*)d_in[base + 0];
        b1[br] = (const float*)d_in[base + 1];
        g1[br] = (const float*)d_in[base + 2];
        bt1[br] = (const float*)d_in[base + 3];
        W2[br] = (const float*)d_in[base + 4];
        b2[br] = (const float*)d_in[base + 5];
        g2[br] = (const float*)d_in[base + 6];
        bt2[br] = (const float*)d_in[base + 7];
    }
    const float* gW1 = (const float*)d_in[21];
    const float* gb1 = (const float*)d_in[22];
    const float* pa  = (const float*)d_in[23];
    const float* gW2 = (const float*)d_in[24];
    const float* gb2 = (const float*)d_in[25];
    const float* fcW = (const float*)d_in[26];
    const float* fcb = (const float*)d_in[27];
    float* out = (float*)d_out;

    // ws carve (~54 MB)
    char* p = (char*)d_ws;
    auto take = [&](size_t bytes) { char* r = p; p += (bytes + 255) & ~(size_t)255; return r; };
    size_t NHb = (size_t)N * HD * 2;  // bf16 table bytes
    short* X    = (short*)take(NHb);
    short* Yraw = (short*)take(NHb);
    short* Hbn[2];
    Hbn[0] = (short*)take(NHb);
    Hbn[1] = (short*)take(NHb);
    float* ns = (float*)take((size_t)N * 4);
    float* nd = (float*)take((size_t)N * 4);
    float* stats = (float*)take(512);
    int* dego = (int*)take((size_t)N * 4);
    int* degi = (int*)take((size_t)N * 4);
    int* cursor = (int*)take((size_t)N * 4);
    int* rowptr = (int*)take((size_t)(N + 1) * 4);
    int* bsums = (int*)take(4096);
    // carve from d_out (dead until k_fc): Z (12.8MB) + col (5MB)
    short* Z = (short*)d_out;
    int* col = (int*)((char*)d_out + NHb);

    int gE = (E + 255) / 256;
    int gN = (N + 255) / 256;
    int nScanBlk = (N + 1023) / 1024;
    int gEW = (N * 8 + 255) / 256;  // elementwise over N*8

    for (int br = 0; br < 2; ++br) {
        hipMemsetAsync(dego, 0, (size_t)N * 4, stream);
        hipMemsetAsync(degi, 0, (size_t)N * 4, stream);
        k_deg<<<gE, 256, 0, stream>>>(srcs[br], dsts[br], dego, degi, E);
        k_norms<<<gN, 256, 0, stream>>>(dego, degi, ns, nd, N);
        k_scan_local<<<nScanBlk, 1024, 0, stream>>>(degi, rowptr, bsums, N);
        k_scan_tops<<<1, 1024, 0, stream>>>(bsums, nScanBlk);
        k_scan_add<<<gN, 256, 0, stream>>>(rowptr, bsums, N, E);
        hipMemsetAsync(cursor, 0, (size_t)N * 4, stream);
        k_csr_fill<<<gE, 256, 0, stream>>>(srcs[br], dsts[br], rowptr, cursor, col, E);

        // layer 1
        k_scale_nf<<<gEW, 256, 0, stream>>>(nf, ns, Yraw);          // Yraw <- bf16(nf*ns)
        k_gather<<<(N * 64) / 256, 256, 0, stream>>>(Yraw, nd, rowptr, col, X);
        hipMemsetAsync(stats, 0, 512, stream);
        k_lin<<<GRID_T, 256, 0, stream>>>(X, W1[br], b1[br], Yraw, stats);
        k_bnb<<<gEW, 256, 0, stream>>>(Yraw, Hbn[br], stats, g1[br], bt1[br], ns);  // temp, ns-folded

        // layer 2
        k_gather<<<(N * 64) / 256, 256, 0, stream>>>(Hbn[br], nd, rowptr, col, X);
        hipMemsetAsync(stats, 0, 512, stream);
        k_lin<<<GRID_T, 256, 0, stream>>>(X, W2[br], b2[br], Yraw, stats);
        k_bnb<<<gEW, 256, 0, stream>>>(Yraw, Hbn[br], stats, g2[br], bt2[br], (const float*)nullptr);
    }

    k_comb1<<<GRID_T, 256, 0, stream>>>(Hbn[0], Hbn[1], gW1, gb1, pa, Z);
    k_comb2<<<GRID_T, 256, 0, stream>>>(Z, gW2, gb2, X);             // X = gate
    k_fc<<<GRID_T, 256, 0, stream>>>(X, Hbn[0], Hbn[1], fcW, fcb, out);
}

// Round 4
// 620.282 us; speedup vs baseline: 2.9606x; 1.2812x over previous
//
#include <hip/hip_runtime.h>
#include <math.h>

#define NN 100000
#define NE 1250000
#define HD 64
#define NCLS 129
#define NTILES 6250      // NN / 16
#define GRID_T 782       // 3128 waves -> ~2 tiles each
#define HB 32            // histogram edge-chunks
#define HS 8             // node subranges
#define HBINS 12500      // NN / HS
#define HCH ((NE + HB - 1) / HB)

typedef float f32x4 __attribute__((ext_vector_type(4)));
typedef short bf16x8 __attribute__((ext_vector_type(8)));

__device__ __forceinline__ short f2b(float f) {
    unsigned u = __builtin_bit_cast(unsigned, f);
    u += 0x7FFFu + ((u >> 16) & 1u);
    return (short)(u >> 16);
}
__device__ __forceinline__ float b2f(short s) {
    return __builtin_bit_cast(float, ((unsigned)(unsigned short)s) << 16);
}

// ---------------- LDS-privatized degree histograms (no global atomics) ----------
// grid: (b=HB chunks, s=HS subranges, a=2 arrays). P[a][b][node] partials.
__global__ __launch_bounds__(1024) void k_hist(
    const int* __restrict__ idx_dst, const int* __restrict__ idx_src,
    int* __restrict__ P) {
    __shared__ int h[HBINS];
    int b = blockIdx.x, s = blockIdx.y, a = blockIdx.z;
    const int* __restrict__ idx = a ? idx_src : idx_dst;
    for (int i = threadIdx.x; i < HBINS; i += 1024) h[i] = 0;
    __syncthreads();
    int lo = s * HBINS;
    int beg = b * HCH, end = beg + HCH;
    if (end > NE) end = NE;
    for (int i = beg + threadIdx.x; i < end; i += 1024) {
        int v = idx[i] - lo;
        if ((unsigned)v < (unsigned)HBINS) atomicAdd(&h[v], 1);
    }
    __syncthreads();
    int* dst = P + ((size_t)(a * HB + b)) * NN + lo;
    for (int i = threadIdx.x; i < HBINS; i += 1024) dst[i] = h[i];
}

// reduce partials over b; emit degi (for scan) + ns/nd
__global__ void k_reduce_norms(const int* __restrict__ P, float* __restrict__ ns,
                               float* __restrict__ nd, int* __restrict__ degi) {
    int node = blockIdx.x * 256 + threadIdx.x;
    if (node >= NN) return;
    int din = 0, dout = 0;
#pragma unroll
    for (int b = 0; b < HB; ++b) {
        din  += P[(size_t)b * NN + node];
        dout += P[(size_t)(HB + b) * NN + node];
    }
    degi[node] = din;
    int a = dout < 1 ? 1 : dout;
    int c = din  < 1 ? 1 : din;
    ns[node] = rsqrtf((float)a);
    nd[node] = rsqrtf((float)c);
}

// ---------------- prefix scan (3-phase) ----------------
__global__ void k_scan_local(const int* __restrict__ deg, int* __restrict__ excl,
                             int* __restrict__ bsums, int n) {
    __shared__ int sm[1024];
    int t = threadIdx.x;
    int i = blockIdx.x * 1024 + t;
    int v = (i < n) ? deg[i] : 0;
    sm[t] = v;
    __syncthreads();
    for (int ofs = 1; ofs < 1024; ofs <<= 1) {
        int x = (t >= ofs) ? sm[t - ofs] : 0;
        __syncthreads();
        sm[t] += x;
        __syncthreads();
    }
    if (i < n) excl[i] = sm[t] - v;
    if (t == 1023) bsums[blockIdx.x] = sm[1023];
}

__global__ void k_scan_tops(int* __restrict__ bsums, int nb) {
    __shared__ int sm[1024];
    int t = threadIdx.x;
    int v = (t < nb) ? bsums[t] : 0;
    sm[t] = v;
    __syncthreads();
    for (int ofs = 1; ofs < 1024; ofs <<= 1) {
        int x = (t >= ofs) ? sm[t - ofs] : 0;
        __syncthreads();
        sm[t] += x;
        __syncthreads();
    }
    if (t < nb) bsums[t] = sm[t] - v;  // exclusive
}

__global__ void k_scan_add(int* __restrict__ excl, const int* __restrict__ bsums,
                           int n, int total) {
    int i = blockIdx.x * blockDim.x + threadIdx.x;
    if (i < n) excl[i] += bsums[i >> 10];
    if (i == 0) excl[n] = total;
}

__global__ void k_csr_fill(const int* __restrict__ src, const int* __restrict__ dst,
                           const int* __restrict__ rowptr, int* __restrict__ cursor,
                           int* __restrict__ col, int e) {
    int i = blockIdx.x * blockDim.x + threadIdx.x;
    if (i < e) {
        int d = dst[i];
        int p = atomicAdd(&cursor[d], 1);
        col[rowptr[d] + p] = src[i];
    }
}

// ---------------- prescale node_features by ns -> bf16 table ----------------
__global__ void k_scale_nf(const float* __restrict__ nf, const float* __restrict__ ns,
                           short* __restrict__ T) {
    int i = blockIdx.x * blockDim.x + threadIdx.x;  // NN*8 threads, 8 elems each
    if (i >= NN * 8) return;
    int node = i >> 3;
    float s = ns[node];
    const float4* p = (const float4*)(nf + (size_t)i * 8);
    float4 a = p[0], b = p[1];
    short r[8];
    r[0] = f2b(a.x * s); r[1] = f2b(a.y * s); r[2] = f2b(a.z * s); r[3] = f2b(a.w * s);
    r[4] = f2b(b.x * s); r[5] = f2b(b.y * s); r[6] = f2b(b.z * s); r[7] = f2b(b.w * s);
    *(bf16x8*)(T + (size_t)i * 8) = *(bf16x8*)r;
}

// ---------------- gather: out[w] = nd[w] * sum_{c in N(w)} tab[c]  (tab pre-scaled by ns)
__global__ __launch_bounds__(256) void k_gather(
    const short* __restrict__ tab, const float* __restrict__ nd,
    const int* __restrict__ rowptr, const int* __restrict__ col,
    short* __restrict__ out) {
    int w = (blockIdx.x * 256 + threadIdx.x) >> 6;
    int lane = threadIdx.x & 63;
    if (w >= NN) return;
    int beg = rowptr[w], end = rowptr[w + 1];
    float s = 0.f;
    for (int e0 = beg; e0 < end; e0 += 64) {
        int cnt = end - e0; if (cnt > 64) cnt = 64;
        int myc = (lane < cnt) ? col[e0 + lane] : 0;
        for (int j = 0; j < cnt; j += 8) {
#pragma unroll
            for (int u = 0; u < 8; ++u) {
                int c = __shfl(myc, j + u, 64);
                float v = b2f(tab[(size_t)c * HD + lane]);
                s += (j + u < cnt) ? v : 0.f;
            }
        }
    }
    out[(size_t)w * HD + lane] = f2b(s * nd[w]);
}

// ---------------- MFMA linear 64->64 + bias + ELU + column stats ----------------
__global__ __launch_bounds__(256) void k_lin(
    const short* __restrict__ X, const float* __restrict__ W,
    const float* __restrict__ bias, short* __restrict__ Y,
    float* __restrict__ stats) {
    __shared__ short sW[4096];
    __shared__ float sm2[128];
    int t = threadIdx.x;
    for (int i = t; i < 4096; i += 256) {
        int j = i & 7, l16i = (i >> 3) & 15, kgi = (i >> 7) & 3, kbi = (i >> 9) & 1, oti = (i >> 10) & 3;
        sW[i] = f2b(W[(kbi * 32 + kgi * 8 + j) * HD + oti * 16 + l16i]);
    }
    if (t < 128) sm2[t] = 0.f;
    __syncthreads();
    int lane = t & 63, wv = t >> 6, l16 = lane & 15, kg = lane >> 4;
    bf16x8 bfrag[2][4];
#pragma unroll
    for (int kb = 0; kb < 2; ++kb)
#pragma unroll
        for (int ot = 0; ot < 4; ++ot)
            bfrag[kb][ot] = *(const bf16x8*)&sW[((ot * 2 + kb) * 4 + kg) * 128 + l16 * 8];
    float bo[4];
#pragma unroll
    for (int ot = 0; ot < 4; ++ot) bo[ot] = bias[ot * 16 + l16];
    float ps[4] = {0.f, 0.f, 0.f, 0.f}, pq[4] = {0.f, 0.f, 0.f, 0.f};
    for (int tile = blockIdx.x * 4 + wv; tile < NTILES; tile += GRID_T * 4) {
        const short* xp = X + ((size_t)tile * 16 + l16) * HD + kg * 8;
        bf16x8 a0 = *(const bf16x8*)xp;
        bf16x8 a1 = *(const bf16x8*)(xp + 32);
        f32x4 acc[4];
#pragma unroll
        for (int ot = 0; ot < 4; ++ot) {
            acc[ot] = (f32x4){0.f, 0.f, 0.f, 0.f};
            acc[ot] = __builtin_amdgcn_mfma_f32_16x16x32_bf16(a0, bfrag[0][ot], acc[ot], 0, 0, 0);
            acc[ot] = __builtin_amdgcn_mfma_f32_16x16x32_bf16(a1, bfrag[1][ot], acc[ot], 0, 0, 0);
        }
#pragma unroll
        for (int ot = 0; ot < 4; ++ot) {
#pragma unroll
            for (int r = 0; r < 4; ++r) {
                float y = acc[ot][r] + bo[ot];
                y = y > 0.f ? y : expm1f(y);
                ps[ot] += y; pq[ot] += y * y;
                Y[((size_t)tile * 16 + kg * 4 + r) * HD + ot * 16 + l16] = f2b(y);
            }
        }
    }
#pragma unroll
    for (int ot = 0; ot < 4; ++ot) {
        atomicAdd(&sm2[ot * 16 + l16], ps[ot]);
        atomicAdd(&sm2[64 + ot * 16 + l16], pq[ot]);
    }
    __syncthreads();
    if (t < 128) atomicAdd(&stats[t], sm2[t]);
}

// ---------------- BN apply (bf16 in/out), optional ns fold ----------------
__global__ void k_bnb(const short* __restrict__ Y, short* __restrict__ O,
                      const float* __restrict__ stats, const float* __restrict__ g,
                      const float* __restrict__ bt, const float* __restrict__ ns) {
    int i = blockIdx.x * blockDim.x + threadIdx.x;  // NN*8 threads
    if (i >= NN * 8) return;
    int node = i >> 3;
    int o0 = (i & 7) * 8;
    float extra = ns ? ns[node] : 1.f;
    bf16x8 v = *(const bf16x8*)(Y + (size_t)i * 8);
    short r[8];
    const float invN = 1.f / (float)NN;
#pragma unroll
    for (int j = 0; j < 8; ++j) {
        int o = o0 + j;
        float mu = stats[o] * invN;
        float var = fmaxf(stats[64 + o] * invN - mu * mu, 0.f);
        float isd = rsqrtf(var + 1e-5f);
        float sc = g[o] * isd * extra;
        float sh = (bt[o] - mu * g[o] * isd) * extra;
        r[j] = f2b(b2f(v[j]) * sc + sh);
    }
    *(bf16x8*)(O + (size_t)i * 8) = *(bf16x8*)r;
}

// ---------------- comb1: Z = PReLU(cat(h1,h2,|h1-h2|,h1*h2) @ gW1 + gb1) ----------------
__global__ __launch_bounds__(256) void k_comb1(
    const short* __restrict__ H1, const short* __restrict__ H2,
    const float* __restrict__ W, const float* __restrict__ bias,
    const float* __restrict__ pa, short* __restrict__ Z) {
    __shared__ short sW[16384];
    int t = threadIdx.x;
    for (int i = t; i < 16384; i += 256) {
        int j = i & 7, l16i = (i >> 3) & 15, kgi = (i >> 7) & 3, kbi = (i >> 9) & 7, oti = (i >> 12) & 3;
        sW[i] = f2b(W[(kbi * 32 + kgi * 8 + j) * HD + oti * 16 + l16i]);
    }
    __syncthreads();
    int lane = t & 63, wv = t >> 6, l16 = lane & 15, kg = lane >> 4;
    float slope = pa[0];
    float bo[4];
#pragma unroll
    for (int ot = 0; ot < 4; ++ot) bo[ot] = bias[ot * 16 + l16];
    for (int tile = blockIdx.x * 4 + wv; tile < NTILES; tile += GRID_T * 4) {
        size_t rb = ((size_t)tile * 16 + l16) * HD + kg * 8;
        bf16x8 h1e = *(const bf16x8*)(H1 + rb);
        bf16x8 h1o = *(const bf16x8*)(H1 + rb + 32);
        bf16x8 h2e = *(const bf16x8*)(H2 + rb);
        bf16x8 h2o = *(const bf16x8*)(H2 + rb + 32);
        bf16x8 fe[8];
        fe[0] = h1e; fe[1] = h1o; fe[2] = h2e; fe[3] = h2o;
        short tabs[8], tprd[8];
#pragma unroll
        for (int j = 0; j < 8; ++j) {
            float a = b2f(h1e[j]), b = b2f(h2e[j]);
            tabs[j] = f2b(fabsf(a - b)); tprd[j] = f2b(a * b);
        }
        fe[4] = *(bf16x8*)tabs; fe[6] = *(bf16x8*)tprd;
#pragma unroll
        for (int j = 0; j < 8; ++j) {
            float a = b2f(h1o[j]), b = b2f(h2o[j]);
            tabs[j] = f2b(fabsf(a - b)); tprd[j] = f2b(a * b);
        }
        fe[5] = *(bf16x8*)tabs; fe[7] = *(bf16x8*)tprd;
        f32x4 acc[4];
#pragma unroll
        for (int ot = 0; ot < 4; ++ot) acc[ot] = (f32x4){0.f, 0.f, 0.f, 0.f};
#pragma unroll
        for (int kb = 0; kb < 8; ++kb)
#pragma unroll
            for (int ot = 0; ot < 4; ++ot) {
                bf16x8 bf = *(const bf16x8*)&sW[((ot * 8 + kb) * 4 + kg) * 128 + l16 * 8];
                acc[ot] = __builtin_amdgcn_mfma_f32_16x16x32_bf16(fe[kb], bf, acc[ot], 0, 0, 0);
            }
#pragma unroll
        for (int ot = 0; ot < 4; ++ot)
#pragma unroll
            for (int r = 0; r < 4; ++r) {
                float z = acc[ot][r] + bo[ot];
                z = z > 0.f ? z : slope * z;
                Z[((size_t)tile * 16 + kg * 4 + r) * HD + ot * 16 + l16] = f2b(z);
            }
    }
}

// ---------------- comb2: gate = sigmoid(Z @ gW2 + gb2) ----------------
__global__ __launch_bounds__(256) void k_comb2(
    const short* __restrict__ Z, const float* __restrict__ W,
    const float* __restrict__ bias, short* __restrict__ G) {
    __shared__ short sW[4096];
    int t = threadIdx.x;
    for (int i = t; i < 4096; i += 256) {
        int j = i & 7, l16i = (i >> 3) & 15, kgi = (i >> 7) & 3, kbi = (i >> 9) & 1, oti = (i >> 10) & 3;
        sW[i] = f2b(W[(kbi * 32 + kgi * 8 + j) * HD + oti * 16 + l16i]);
    }
    __syncthreads();
    int lane = t & 63, wv = t >> 6, l16 = lane & 15, kg = lane >> 4;
    bf16x8 bfrag[2][4];
#pragma unroll
    for (int kb = 0; kb < 2; ++kb)
#pragma unroll
        for (int ot = 0; ot < 4; ++ot)
            bfrag[kb][ot] = *(const bf16x8*)&sW[((ot * 2 + kb) * 4 + kg) * 128 + l16 * 8];
    float bo[4];
#pragma unroll
    for (int ot = 0; ot < 4; ++ot) bo[ot] = bias[ot * 16 + l16];
    for (int tile = blockIdx.x * 4 + wv; tile < NTILES; tile += GRID_T * 4) {
        const short* xp = Z + ((size_t)tile * 16 + l16) * HD + kg * 8;
        bf16x8 a0 = *(const bf16x8*)xp;
        bf16x8 a1 = *(const bf16x8*)(xp + 32);
        f32x4 acc[4];
#pragma unroll
        for (int ot = 0; ot < 4; ++ot) {
            acc[ot] = (f32x4){0.f, 0.f, 0.f, 0.f};
            acc[ot] = __builtin_amdgcn_mfma_f32_16x16x32_bf16(a0, bfrag[0][ot], acc[ot], 0, 0, 0);
            acc[ot] = __builtin_amdgcn_mfma_f32_16x16x32_bf16(a1, bfrag[1][ot], acc[ot], 0, 0, 0);
        }
#pragma unroll
        for (int ot = 0; ot < 4; ++ot)
#pragma unroll
            for (int r = 0; r < 4; ++r) {
                float y = acc[ot][r] + bo[ot];
                float gate = 1.f / (1.f + expf(-y));
                G[((size_t)tile * 16 + kg * 4 + r) * HD + ot * 16 + l16] = f2b(gate);
            }
    }
}

// ---------------- fc: out = (g*h1 + (1-g)*h2) @ fcW + fcb ----------------
__global__ __launch_bounds__(256) void k_fc(
    const short* __restrict__ G, const short* __restrict__ H1, const short* __restrict__ H2,
    const float* __restrict__ W, const float* __restrict__ bias,
    float* __restrict__ out) {
    __shared__ short sW[9216];  // 9 ot-tiles x 64 k (cols 129 padded to 144)
    int t = threadIdx.x;
    for (int i = t; i < 9216; i += 256) {
        int j = i & 7, l16i = (i >> 3) & 15, kgi = (i >> 7) & 3, kbi = (i >> 9) & 1, oti = i >> 10;
        int k = kbi * 32 + kgi * 8 + j, o = oti * 16 + l16i;
        sW[i] = (o < NCLS) ? f2b(W[k * NCLS + o]) : (short)0;
    }
    __syncthreads();
    int lane = t & 63, wv = t >> 6, l16 = lane & 15, kg = lane >> 4;
    float bo[9];
#pragma unroll
    for (int ot = 0; ot < 9; ++ot) {
        int o = ot * 16 + l16;
        bo[ot] = (o < NCLS) ? bias[o] : 0.f;
    }
    for (int tile = blockIdx.x * 4 + wv; tile < NTILES; tile += GRID_T * 4) {
        size_t rb = ((size_t)tile * 16 + l16) * HD;
        f32x4 acc[9];
#pragma unroll
        for (int ot = 0; ot < 9; ++ot) acc[ot] = (f32x4){0.f, 0.f, 0.f, 0.f};
#pragma unroll
        for (int kb = 0; kb < 2; ++kb) {
            int koff = kb * 32 + kg * 8;
            bf16x8 gv  = *(const bf16x8*)(G + rb + koff);
            bf16x8 h1v = *(const bf16x8*)(H1 + rb + koff);
            bf16x8 h2v = *(const bf16x8*)(H2 + rb + koff);
            short af[8];
#pragma unroll
            for (int j = 0; j < 8; ++j) {
                float gf = b2f(gv[j]);
                af[j] = f2b(gf * b2f(h1v[j]) + (1.f - gf) * b2f(h2v[j]));
            }
            bf16x8 a = *(bf16x8*)af;
#pragma unroll
            for (int ot = 0; ot < 9; ++ot) {
                bf16x8 bf = *(const bf16x8*)&sW[((ot * 2 + kb) * 4 + kg) * 128 + l16 * 8];
                acc[ot] = __builtin_amdgcn_mfma_f32_16x16x32_bf16(a, bf, acc[ot], 0, 0, 0);
            }
        }
#pragma unroll
        for (int ot = 0; ot < 9; ++ot) {
            int o = ot * 16 + l16;
            if (o < NCLS) {
#pragma unroll
                for (int r = 0; r < 4; ++r) {
                    int node = tile * 16 + kg * 4 + r;
                    out[(size_t)node * NCLS + o] = acc[ot][r] + bo[ot];
                }
            }
        }
    }
}

extern "C" void kernel_launch(void* const* d_in, const int* in_sizes, int n_in,
                              void* d_out, int out_size, void* d_ws, size_t ws_size,
                              hipStream_t stream) {
    (void)in_sizes; (void)n_in; (void)out_size; (void)ws_size;
    const int N = NN, E = NE;

    const float* nf = (const float*)d_in[0];
    const int* srcs[2] = {(const int*)d_in[1], (const int*)d_in[3]};
    const int* dsts[2] = {(const int*)d_in[2], (const int*)d_in[4]};
    const float *W1[2], *b1[2], *g1[2], *bt1[2], *W2[2], *b2[2], *g2[2], *bt2[2];
    for (int br = 0; br < 2; ++br) {
        int base = 5 + br * 8;
        W1[br] = (const float*)d_in[base + 0];
        b1[br] = (const float*)d_in[base + 1];
        g1[br] = (const float*)d_in[base + 2];
        bt1[br] = (const float*)d_in[base + 3];
        W2[br] = (const float*)d_in[base + 4];
        b2[br] = (const float*)d_in[base + 5];
        g2[br] = (const float*)d_in[base + 6];
        bt2[br] = (const float*)d_in[base + 7];
    }
    const float* gW1 = (const float*)d_in[21];
    const float* gb1 = (const float*)d_in[22];
    const float* pa  = (const float*)d_in[23];
    const float* gW2 = (const float*)d_in[24];
    const float* gb2 = (const float*)d_in[25];
    const float* fcW = (const float*)d_in[26];
    const float* fcb = (const float*)d_in[27];
    float* out = (float*)d_out;

    // ws carve (~54 MB)
    char* p = (char*)d_ws;
    auto take = [&](size_t bytes) { char* r = p; p += (bytes + 255) & ~(size_t)255; return r; };
    size_t NHb = (size_t)N * HD * 2;  // bf16 table bytes (12.8 MB)
    short* X    = (short*)take(NHb);
    short* Yraw = (short*)take(NHb);
    short* Hbn[2];
    Hbn[0] = (short*)take(NHb);
    Hbn[1] = (short*)take(NHb);
    float* ns = (float*)take((size_t)N * 4);
    float* nd = (float*)take((size_t)N * 4);
    float* stats = (float*)take(512);
    int* degi = (int*)take((size_t)N * 4);
    int* cursor = (int*)take((size_t)N * 4);
    int* rowptr = (int*)take((size_t)(N + 1) * 4);
    int* bsums = (int*)take(4096);
    // P (degree partials, 2*HB*NN*4B = 25.6 MB) aliases X+Yraw (dead during preprocessing)
    int* P = (int*)X;
    // carve from d_out (dead until k_fc): Z (12.8MB) + col (5MB)
    short* Z = (short*)d_out;
    int* col = (int*)((char*)d_out + NHb);

    int gE = (E + 255) / 256;
    int gN = (N + 255) / 256;
    int nScanBlk = (N + 1023) / 1024;
    int gEW = (N * 8 + 255) / 256;  // elementwise over N*8

    for (int br = 0; br < 2; ++br) {
        // ---- CSR build (atomic-free degree counting) ----
        k_hist<<<dim3(HB, HS, 2), 1024, 0, stream>>>(dsts[br], srcs[br], P);
        k_reduce_norms<<<gN, 256, 0, stream>>>(P, ns, nd, degi);
        k_scan_local<<<nScanBlk, 1024, 0, stream>>>(degi, rowptr, bsums, N);
        k_scan_tops<<<1, 1024, 0, stream>>>(bsums, nScanBlk);
        k_scan_add<<<gN, 256, 0, stream>>>(rowptr, bsums, N, E);
        hipMemsetAsync(cursor, 0, (size_t)N * 4, stream);
        k_csr_fill<<<gE, 256, 0, stream>>>(srcs[br], dsts[br], rowptr, cursor, col, E);

        // layer 1
        k_scale_nf<<<gEW, 256, 0, stream>>>(nf, ns, Yraw);          // Yraw <- bf16(nf*ns)
        k_gather<<<(N * 64) / 256, 256, 0, stream>>>(Yraw, nd, rowptr, col, X);
        hipMemsetAsync(stats, 0, 512, stream);
        k_lin<<<GRID_T, 256, 0, stream>>>(X, W1[br], b1[br], Yraw, stats);
        k_bnb<<<gEW, 256, 0, stream>>>(Yraw, Hbn[br], stats, g1[br], bt1[br], ns);  // temp, ns-folded

        // layer 2
        k_gather<<<(N * 64) / 256, 256, 0, stream>>>(Hbn[br], nd, rowptr, col, X);
        hipMemsetAsync(stats, 0, 512, stream);
        k_lin<<<GRID_T, 256, 0, stream>>>(X, W2[br], b2[br], Yraw, stats);
        k_bnb<<<gEW, 256, 0, stream>>>(Yraw, Hbn[br], stats, g2[br], bt2[br], (const float*)nullptr);
    }

    k_comb1<<<GRID_T, 256, 0, stream>>>(Hbn[0], Hbn[1], gW1, gb1, pa, Z);
    k_comb2<<<GRID_T, 256, 0, stream>>>(Z, gW2, gb2, X);             // X = gate
    k_fc<<<GRID_T, 256, 0, stream>>>(X, Hbn[0], Hbn[1], fcW, fcb, out);
}

// Round 5
// 529.528 us; speedup vs baseline: 3.4680x; 1.1714x over previous
//
#include <hip/hip_runtime.h>
#include <math.h>

#define NN 100000
#define NE 1250000
#define HD 64
#define NCLS 129
#define NTILES 6250      // NN / 16
#define GRID_T 782       // 3128 waves -> ~2 tiles each
#define HB 32            // histogram edge-chunks
#define HS 8             // node subranges
#define HBINS 12500      // NN / HS
#define HCH ((NE + HB - 1) / HB)

typedef float f32x4 __attribute__((ext_vector_type(4)));
typedef short bf16x8 __attribute__((ext_vector_type(8)));

__device__ __forceinline__ short f2b(float f) {
    unsigned u = __builtin_bit_cast(unsigned, f);
    u += 0x7FFFu + ((u >> 16) & 1u);
    return (short)(u >> 16);
}
__device__ __forceinline__ float b2f(short s) {
    return __builtin_bit_cast(float, ((unsigned)(unsigned short)s) << 16);
}

// ---------------- LDS-privatized degree histograms (no global atomics) ----------
// grid: (b=HB chunks, s=HS subranges, a=2 arrays). P[a][b][node] partials.
__global__ __launch_bounds__(1024) void k_hist(
    const int* __restrict__ idx_dst, const int* __restrict__ idx_src,
    int* __restrict__ P) {
    __shared__ int h[HBINS];
    int b = blockIdx.x, s = blockIdx.y, a = blockIdx.z;
    const int* __restrict__ idx = a ? idx_src : idx_dst;
    for (int i = threadIdx.x; i < HBINS; i += 1024) h[i] = 0;
    __syncthreads();
    int lo = s * HBINS;
    int beg = b * HCH, end = beg + HCH;
    if (end > NE) end = NE;
    for (int i = beg + threadIdx.x; i < end; i += 1024) {
        int v = idx[i] - lo;
        if ((unsigned)v < (unsigned)HBINS) atomicAdd(&h[v], 1);
    }
    __syncthreads();
    int* dst = P + ((size_t)(a * HB + b)) * NN + lo;
    for (int i = threadIdx.x; i < HBINS; i += 1024) dst[i] = h[i];
}

// reduce partials over b; emit degi + ns/nd; ALSO convert dst-partials P[0..HB)
// into an exclusive prefix over b (per node) for the atomic-free CSR fill.
__global__ void k_reduce_norms(int* __restrict__ P, float* __restrict__ ns,
                               float* __restrict__ nd, int* __restrict__ degi) {
    int node = blockIdx.x * 256 + threadIdx.x;
    if (node >= NN) return;
    int din = 0, dout = 0;
#pragma unroll
    for (int b = 0; b < HB; ++b) {
        int v = P[(size_t)b * NN + node];
        P[(size_t)b * NN + node] = din;   // exclusive prefix over chunks
        din += v;
        dout += P[(size_t)(HB + b) * NN + node];
    }
    degi[node] = din;
    int a = dout < 1 ? 1 : dout;
    int c = din  < 1 ? 1 : din;
    ns[node] = rsqrtf((float)a);
    nd[node] = rsqrtf((float)c);
}

// ---------------- prefix scan (3-phase) ----------------
__global__ void k_scan_local(const int* __restrict__ deg, int* __restrict__ excl,
                             int* __restrict__ bsums, int n) {
    __shared__ int sm[1024];
    int t = threadIdx.x;
    int i = blockIdx.x * 1024 + t;
    int v = (i < n) ? deg[i] : 0;
    sm[t] = v;
    __syncthreads();
    for (int ofs = 1; ofs < 1024; ofs <<= 1) {
        int x = (t >= ofs) ? sm[t - ofs] : 0;
        __syncthreads();
        sm[t] += x;
        __syncthreads();
    }
    if (i < n) excl[i] = sm[t] - v;
    if (t == 1023) bsums[blockIdx.x] = sm[1023];
}

__global__ void k_scan_tops(int* __restrict__ bsums, int nb) {
    __shared__ int sm[1024];
    int t = threadIdx.x;
    int v = (t < nb) ? bsums[t] : 0;
    sm[t] = v;
    __syncthreads();
    for (int ofs = 1; ofs < 1024; ofs <<= 1) {
        int x = (t >= ofs) ? sm[t - ofs] : 0;
        __syncthreads();
        sm[t] += x;
        __syncthreads();
    }
    if (t < nb) bsums[t] = sm[t] - v;  // exclusive
}

__global__ void k_scan_add(int* __restrict__ excl, const int* __restrict__ bsums,
                           int n, int total) {
    int i = blockIdx.x * blockDim.x + threadIdx.x;
    if (i < n) excl[i] += bsums[i >> 10];
    if (i == 0) excl[n] = total;
}

// ---------------- atomic-free CSR fill: block (b,s) re-scans chunk b, LDS cursor
__global__ __launch_bounds__(1024) void k_fill(
    const int* __restrict__ dst, const int* __restrict__ src,
    const int* __restrict__ rowptr, const int* __restrict__ Pofs,
    int* __restrict__ col) {
    __shared__ int cur[HBINS];
    int b = blockIdx.x, s = blockIdx.y;
    int lo = s * HBINS;
    for (int i = threadIdx.x; i < HBINS; i += 1024) cur[i] = 0;
    __syncthreads();
    int beg = b * HCH, end = beg + HCH;
    if (end > NE) end = NE;
    const int* __restrict__ ofs = Pofs + (size_t)b * NN;
    for (int i = beg + threadIdx.x; i < end; i += 1024) {
        int d = dst[i] - lo;
        if ((unsigned)d < (unsigned)HBINS) {
            int r = atomicAdd(&cur[d], 1);
            int node = d + lo;
            col[rowptr[node] + ofs[node] + r] = src[i];
        }
    }
}

// ---------------- prescale node_features by ns -> bf16 table ----------------
__global__ void k_scale_nf(const float* __restrict__ nf, const float* __restrict__ ns,
                           short* __restrict__ T) {
    int i = blockIdx.x * blockDim.x + threadIdx.x;  // NN*8 threads, 8 elems each
    if (i >= NN * 8) return;
    int node = i >> 3;
    float s = ns[node];
    const float4* p = (const float4*)(nf + (size_t)i * 8);
    float4 a = p[0], b = p[1];
    short r[8];
    r[0] = f2b(a.x * s); r[1] = f2b(a.y * s); r[2] = f2b(a.z * s); r[3] = f2b(a.w * s);
    r[4] = f2b(b.x * s); r[5] = f2b(b.y * s); r[6] = f2b(b.z * s); r[7] = f2b(b.w * s);
    *(bf16x8*)(T + (size_t)i * 8) = *(bf16x8*)r;
}

// ---------------- gather: out[w] = nd[w] * sum_{c in N(w)} tab[c]  (tab pre-scaled by ns)
__global__ __launch_bounds__(256) void k_gather(
    const short* __restrict__ tab, const float* __restrict__ nd,
    const int* __restrict__ rowptr, const int* __restrict__ col,
    short* __restrict__ out) {
    int w = (blockIdx.x * 256 + threadIdx.x) >> 6;
    int lane = threadIdx.x & 63;
    if (w >= NN) return;
    int beg = rowptr[w], end = rowptr[w + 1];
    float s = 0.f;
    for (int e0 = beg; e0 < end; e0 += 64) {
        int cnt = end - e0; if (cnt > 64) cnt = 64;
        int myc = (lane < cnt) ? col[e0 + lane] : 0;
        for (int j = 0; j < cnt; j += 8) {
#pragma unroll
            for (int u = 0; u < 8; ++u) {
                int c = __shfl(myc, j + u, 64);
                float v = b2f(tab[(size_t)c * HD + lane]);
                s += (j + u < cnt) ? v : 0.f;
            }
        }
    }
    out[(size_t)w * HD + lane] = f2b(s * nd[w]);
}

// ---------------- MFMA linear 64->64 + bias + ELU + column stats ----------------
__global__ __launch_bounds__(256) void k_lin(
    const short* __restrict__ X, const float* __restrict__ W,
    const float* __restrict__ bias, short* __restrict__ Y,
    float* __restrict__ stats) {
    __shared__ short sW[4096];
    __shared__ float sm2[128];
    int t = threadIdx.x;
    for (int i = t; i < 4096; i += 256) {
        int j = i & 7, l16i = (i >> 3) & 15, kgi = (i >> 7) & 3, kbi = (i >> 9) & 1, oti = (i >> 10) & 3;
        sW[i] = f2b(W[(kbi * 32 + kgi * 8 + j) * HD + oti * 16 + l16i]);
    }
    if (t < 128) sm2[t] = 0.f;
    __syncthreads();
    int lane = t & 63, wv = t >> 6, l16 = lane & 15, kg = lane >> 4;
    bf16x8 bfrag[2][4];
#pragma unroll
    for (int kb = 0; kb < 2; ++kb)
#pragma unroll
        for (int ot = 0; ot < 4; ++ot)
            bfrag[kb][ot] = *(const bf16x8*)&sW[((ot * 2 + kb) * 4 + kg) * 128 + l16 * 8];
    float bo[4];
#pragma unroll
    for (int ot = 0; ot < 4; ++ot) bo[ot] = bias[ot * 16 + l16];
    float ps[4] = {0.f, 0.f, 0.f, 0.f}, pq[4] = {0.f, 0.f, 0.f, 0.f};
    for (int tile = blockIdx.x * 4 + wv; tile < NTILES; tile += GRID_T * 4) {
        const short* xp = X + ((size_t)tile * 16 + l16) * HD + kg * 8;
        bf16x8 a0 = *(const bf16x8*)xp;
        bf16x8 a1 = *(const bf16x8*)(xp + 32);
        f32x4 acc[4];
#pragma unroll
        for (int ot = 0; ot < 4; ++ot) {
            acc[ot] = (f32x4){0.f, 0.f, 0.f, 0.f};
            acc[ot] = __builtin_amdgcn_mfma_f32_16x16x32_bf16(a0, bfrag[0][ot], acc[ot], 0, 0, 0);
            acc[ot] = __builtin_amdgcn_mfma_f32_16x16x32_bf16(a1, bfrag[1][ot], acc[ot], 0, 0, 0);
        }
#pragma unroll
        for (int ot = 0; ot < 4; ++ot) {
#pragma unroll
            for (int r = 0; r < 4; ++r) {
                float y = acc[ot][r] + bo[ot];
                y = y > 0.f ? y : expm1f(y);
                ps[ot] += y; pq[ot] += y * y;
                Y[((size_t)tile * 16 + kg * 4 + r) * HD + ot * 16 + l16] = f2b(y);
            }
        }
    }
#pragma unroll
    for (int ot = 0; ot < 4; ++ot) {
        atomicAdd(&sm2[ot * 16 + l16], ps[ot]);
        atomicAdd(&sm2[64 + ot * 16 + l16], pq[ot]);
    }
    __syncthreads();
    if (t < 128) atomicAdd(&stats[t], sm2[t]);
}

// ---------------- BN apply (bf16 in/out), optional ns fold ----------------
__global__ void k_bnb(const short* __restrict__ Y, short* __restrict__ O,
                      const float* __restrict__ stats, const float* __restrict__ g,
                      const float* __restrict__ bt, const float* __restrict__ ns) {
    int i = blockIdx.x * blockDim.x + threadIdx.x;  // NN*8 threads
    if (i >= NN * 8) return;
    int node = i >> 3;
    int o0 = (i & 7) * 8;
    float extra = ns ? ns[node] : 1.f;
    bf16x8 v = *(const bf16x8*)(Y + (size_t)i * 8);
    short r[8];
    const float invN = 1.f / (float)NN;
#pragma unroll
    for (int j = 0; j < 8; ++j) {
        int o = o0 + j;
        float mu = stats[o] * invN;
        float var = fmaxf(stats[64 + o] * invN - mu * mu, 0.f);
        float isd = rsqrtf(var + 1e-5f);
        float sc = g[o] * isd * extra;
        float sh = (bt[o] - mu * g[o] * isd) * extra;
        r[j] = f2b(b2f(v[j]) * sc + sh);
    }
    *(bf16x8*)(O + (size_t)i * 8) = *(bf16x8*)r;
}

// ---------------- comb1: Z = PReLU(cat(h1,h2,|h1-h2|,h1*h2) @ gW1 + gb1) ----------------
__global__ __launch_bounds__(256) void k_comb1(
    const short* __restrict__ H1, const short* __restrict__ H2,
    const float* __restrict__ W, const float* __restrict__ bias,
    const float* __restrict__ pa, short* __restrict__ Z) {
    __shared__ short sW[16384];
    int t = threadIdx.x;
    for (int i = t; i < 16384; i += 256) {
        int j = i & 7, l16i = (i >> 3) & 15, kgi = (i >> 7) & 3, kbi = (i >> 9) & 7, oti = (i >> 12) & 3;
        sW[i] = f2b(W[(kbi * 32 + kgi * 8 + j) * HD + oti * 16 + l16i]);
    }
    __syncthreads();
    int lane = t & 63, wv = t >> 6, l16 = lane & 15, kg = lane >> 4;
    float slope = pa[0];
    float bo[4];
#pragma unroll
    for (int ot = 0; ot < 4; ++ot) bo[ot] = bias[ot * 16 + l16];
    for (int tile = blockIdx.x * 4 + wv; tile < NTILES; tile += GRID_T * 4) {
        size_t rb = ((size_t)tile * 16 + l16) * HD + kg * 8;
        bf16x8 h1e = *(const bf16x8*)(H1 + rb);
        bf16x8 h1o = *(const bf16x8*)(H1 + rb + 32);
        bf16x8 h2e = *(const bf16x8*)(H2 + rb);
        bf16x8 h2o = *(const bf16x8*)(H2 + rb + 32);
        bf16x8 fe[8];
        fe[0] = h1e; fe[1] = h1o; fe[2] = h2e; fe[3] = h2o;
        short tabs[8], tprd[8];
#pragma unroll
        for (int j = 0; j < 8; ++j) {
            float a = b2f(h1e[j]), b = b2f(h2e[j]);
            tabs[j] = f2b(fabsf(a - b)); tprd[j] = f2b(a * b);
        }
        fe[4] = *(bf16x8*)tabs; fe[6] = *(bf16x8*)tprd;
#pragma unroll
        for (int j = 0; j < 8; ++j) {
            float a = b2f(h1o[j]), b = b2f(h2o[j]);
            tabs[j] = f2b(fabsf(a - b)); tprd[j] = f2b(a * b);
        }
        fe[5] = *(bf16x8*)tabs; fe[7] = *(bf16x8*)tprd;
        f32x4 acc[4];
#pragma unroll
        for (int ot = 0; ot < 4; ++ot) acc[ot] = (f32x4){0.f, 0.f, 0.f, 0.f};
#pragma unroll
        for (int kb = 0; kb < 8; ++kb)
#pragma unroll
            for (int ot = 0; ot < 4; ++ot) {
                bf16x8 bf = *(const bf16x8*)&sW[((ot * 8 + kb) * 4 + kg) * 128 + l16 * 8];
                acc[ot] = __builtin_amdgcn_mfma_f32_16x16x32_bf16(fe[kb], bf, acc[ot], 0, 0, 0);
            }
#pragma unroll
        for (int ot = 0; ot < 4; ++ot)
#pragma unroll
            for (int r = 0; r < 4; ++r) {
                float z = acc[ot][r] + bo[ot];
                z = z > 0.f ? z : slope * z;
                Z[((size_t)tile * 16 + kg * 4 + r) * HD + ot * 16 + l16] = f2b(z);
            }
    }
}

// ---------------- comb2: gate = sigmoid(Z @ gW2 + gb2) ----------------
__global__ __launch_bounds__(256) void k_comb2(
    const short* __restrict__ Z, const float* __restrict__ W,
    const float* __restrict__ bias, short* __restrict__ G) {
    __shared__ short sW[4096];
    int t = threadIdx.x;
    for (int i = t; i < 4096; i += 256) {
        int j = i & 7, l16i = (i >> 3) & 15, kgi = (i >> 7) & 3, kbi = (i >> 9) & 1, oti = (i >> 10) & 3;
        sW[i] = f2b(W[(kbi * 32 + kgi * 8 + j) * HD + oti * 16 + l16i]);
    }
    __syncthreads();
    int lane = t & 63, wv = t >> 6, l16 = lane & 15, kg = lane >> 4;
    bf16x8 bfrag[2][4];
#pragma unroll
    for (int kb = 0; kb < 2; ++kb)
#pragma unroll
        for (int ot = 0; ot < 4; ++ot)
            bfrag[kb][ot] = *(const bf16x8*)&sW[((ot * 2 + kb) * 4 + kg) * 128 + l16 * 8];
    float bo[4];
#pragma unroll
    for (int ot = 0; ot < 4; ++ot) bo[ot] = bias[ot * 16 + l16];
    for (int tile = blockIdx.x * 4 + wv; tile < NTILES; tile += GRID_T * 4) {
        const short* xp = Z + ((size_t)tile * 16 + l16) * HD + kg * 8;
        bf16x8 a0 = *(const bf16x8*)xp;
        bf16x8 a1 = *(const bf16x8*)(xp + 32);
        f32x4 acc[4];
#pragma unroll
        for (int ot = 0; ot < 4; ++ot) {
            acc[ot] = (f32x4){0.f, 0.f, 0.f, 0.f};
            acc[ot] = __builtin_amdgcn_mfma_f32_16x16x32_bf16(a0, bfrag[0][ot], acc[ot], 0, 0, 0);
            acc[ot] = __builtin_amdgcn_mfma_f32_16x16x32_bf16(a1, bfrag[1][ot], acc[ot], 0, 0, 0);
        }
#pragma unroll
        for (int ot = 0; ot < 4; ++ot)
#pragma unroll
            for (int r = 0; r < 4; ++r) {
                float y = acc[ot][r] + bo[ot];
                float gate = 1.f / (1.f + expf(-y));
                G[((size_t)tile * 16 + kg * 4 + r) * HD + ot * 16 + l16] = f2b(gate);
            }
    }
}

// ---------------- fc: out = (g*h1 + (1-g)*h2) @ fcW + fcb ----------------
__global__ __launch_bounds__(256) void k_fc(
    const short* __restrict__ G, const short* __restrict__ H1, const short* __restrict__ H2,
    const float* __restrict__ W, const float* __restrict__ bias,
    float* __restrict__ out) {
    __shared__ short sW[9216];  // 9 ot-tiles x 64 k (cols 129 padded to 144)
    int t = threadIdx.x;
    for (int i = t; i < 9216; i += 256) {
        int j = i & 7, l16i = (i >> 3) & 15, kgi = (i >> 7) & 3, kbi = (i >> 9) & 1, oti = i >> 10;
        int k = kbi * 32 + kgi * 8 + j, o = oti * 16 + l16i;
        sW[i] = (o < NCLS) ? f2b(W[k * NCLS + o]) : (short)0;
    }
    __syncthreads();
    int lane = t & 63, wv = t >> 6, l16 = lane & 15, kg = lane >> 4;
    float bo[9];
#pragma unroll
    for (int ot = 0; ot < 9; ++ot) {
        int o = ot * 16 + l16;
        bo[ot] = (o < NCLS) ? bias[o] : 0.f;
    }
    for (int tile = blockIdx.x * 4 + wv; tile < NTILES; tile += GRID_T * 4) {
        size_t rb = ((size_t)tile * 16 + l16) * HD;
        f32x4 acc[9];
#pragma unroll
        for (int ot = 0; ot < 9; ++ot) acc[ot] = (f32x4){0.f, 0.f, 0.f, 0.f};
#pragma unroll
        for (int kb = 0; kb < 2; ++kb) {
            int koff = kb * 32 + kg * 8;
            bf16x8 gv  = *(const bf16x8*)(G + rb + koff);
            bf16x8 h1v = *(const bf16x8*)(H1 + rb + koff);
            bf16x8 h2v = *(const bf16x8*)(H2 + rb + koff);
            short af[8];
#pragma unroll
            for (int j = 0; j < 8; ++j) {
                float gf = b2f(gv[j]);
                af[j] = f2b(gf * b2f(h1v[j]) + (1.f - gf) * b2f(h2v[j]));
            }
            bf16x8 a = *(bf16x8*)af;
#pragma unroll
            for (int ot = 0; ot < 9; ++ot) {
                bf16x8 bf = *(const bf16x8*)&sW[((ot * 2 + kb) * 4 + kg) * 128 + l16 * 8];
                acc[ot] = __builtin_amdgcn_mfma_f32_16x16x32_bf16(a, bf, acc[ot], 0, 0, 0);
            }
        }
#pragma unroll
        for (int ot = 0; ot < 9; ++ot) {
            int o = ot * 16 + l16;
            if (o < NCLS) {
#pragma unroll
                for (int r = 0; r < 4; ++r) {
                    int node = tile * 16 + kg * 4 + r;
                    out[(size_t)node * NCLS + o] = acc[ot][r] + bo[ot];
                }
            }
        }
    }
}

extern "C" void kernel_launch(void* const* d_in, const int* in_sizes, int n_in,
                              void* d_out, int out_size, void* d_ws, size_t ws_size,
                              hipStream_t stream) {
    (void)in_sizes; (void)n_in; (void)out_size; (void)ws_size;
    const int N = NN, E = NE;

    const float* nf = (const float*)d_in[0];
    const int* srcs[2] = {(const int*)d_in[1], (const int*)d_in[3]};
    const int* dsts[2] = {(const int*)d_in[2], (const int*)d_in[4]};
    const float *W1[2], *b1[2], *g1[2], *bt1[2], *W2[2], *b2[2], *g2[2], *bt2[2];
    for (int br = 0; br < 2; ++br) {
        int base = 5 + br * 8;
        W1[br] = (const float*)d_in[base + 0];
        b1[br] = (const float*)d_in[base + 1];
        g1[br] = (const float*)d_in[base + 2];
        bt1[br] = (const float*)d_in[base + 3];
        W2[br] = (const float*)d_in[base + 4];
        b2[br] = (const float*)d_in[base + 5];
        g2[br] = (const float*)d_in[base + 6];
        bt2[br] = (const float*)d_in[base + 7];
    }
    const float* gW1 = (const float*)d_in[21];
    const float* gb1 = (const float*)d_in[22];
    const float* pa  = (const float*)d_in[23];
    const float* gW2 = (const float*)d_in[24];
    const float* gb2 = (const float*)d_in[25];
    const float* fcW = (const float*)d_in[26];
    const float* fcb = (const float*)d_in[27];
    float* out = (float*)d_out;

    // ws carve (~54 MB)
    char* p = (char*)d_ws;
    auto take = [&](size_t bytes) { char* r = p; p += (bytes + 255) & ~(size_t)255; return r; };
    size_t NHb = (size_t)N * HD * 2;  // bf16 table bytes (12.8 MB)
    short* X    = (short*)take(NHb);
    short* Yraw = (short*)take(NHb);
    short* Hbn[2];
    Hbn[0] = (short*)take(NHb);
    Hbn[1] = (short*)take(NHb);
    float* ns = (float*)take((size_t)N * 4);
    float* nd = (float*)take((size_t)N * 4);
    float* stats = (float*)take(512);
    int* degi = (int*)take((size_t)N * 4);
    int* rowptr = (int*)take((size_t)(N + 1) * 4);
    int* bsums = (int*)take(4096);
    // P (degree partials, 2*HB*NN*4B = 25.6 MB) aliases X+Yraw (dead during preprocessing)
    int* P = (int*)X;
    // carve from d_out (dead until k_fc): Z (12.8MB) + col (5MB)
    short* Z = (short*)d_out;
    int* col = (int*)((char*)d_out + NHb);

    int gN = (N + 255) / 256;
    int nScanBlk = (N + 1023) / 1024;
    int gEW = (N * 8 + 255) / 256;  // elementwise over N*8

    for (int br = 0; br < 2; ++br) {
        // ---- CSR build (no global atomics anywhere) ----
        k_hist<<<dim3(HB, HS, 2), 1024, 0, stream>>>(dsts[br], srcs[br], P);
        k_reduce_norms<<<gN, 256, 0, stream>>>(P, ns, nd, degi);   // also: P[0..HB) -> excl prefix
        k_scan_local<<<nScanBlk, 1024, 0, stream>>>(degi, rowptr, bsums, N);
        k_scan_tops<<<1, 1024, 0, stream>>>(bsums, nScanBlk);
        k_scan_add<<<gN, 256, 0, stream>>>(rowptr, bsums, N, E);
        k_fill<<<dim3(HB, HS), 1024, 0, stream>>>(dsts[br], srcs[br], rowptr, P, col);

        // layer 1
        k_scale_nf<<<gEW, 256, 0, stream>>>(nf, ns, Yraw);          // Yraw <- bf16(nf*ns)
        k_gather<<<(N * 64) / 256, 256, 0, stream>>>(Yraw, nd, rowptr, col, X);
        hipMemsetAsync(stats, 0, 512, stream);
        k_lin<<<GRID_T, 256, 0, stream>>>(X, W1[br], b1[br], Yraw, stats);
        k_bnb<<<gEW, 256, 0, stream>>>(Yraw, Hbn[br], stats, g1[br], bt1[br], ns);  // temp, ns-folded

        // layer 2
        k_gather<<<(N * 64) / 256, 256, 0, stream>>>(Hbn[br], nd, rowptr, col, X);
        hipMemsetAsync(stats, 0, 512, stream);
        k_lin<<<GRID_T, 256, 0, stream>>>(X, W2[br], b2[br], Yraw, stats);
        k_bnb<<<gEW, 256, 0, stream>>>(Yraw, Hbn[br], stats, g2[br], bt2[br], (const float*)nullptr);
    }

    k_comb1<<<GRID_T, 256, 0, stream>>>(Hbn[0], Hbn[1], gW1, gb1, pa, Z);
    k_comb2<<<GRID_T, 256, 0, stream>>>(Z, gW2, gb2, X);             // X = gate
    k_fc<<<GRID_T, 256, 0, stream>>>(X, Hbn[0], Hbn[1], fcW, fcb, out);
}